// Round 12
// baseline (1477.194 us; speedup 1.0000x reference)
//
#include <hip/hip_runtime.h>
#include <stdint.h>

#define Bz 4
#define Sz 1024
#define DIMz 4096
#define Hz 32
#define HDz 128
#define ALz 10

typedef unsigned short u16;
typedef __attribute__((ext_vector_type(8))) short short8;
typedef __attribute__((ext_vector_type(4))) float fx4;

__device__ __forceinline__ u16 f2b(float f){
  union { float f; unsigned u; } v; v.f = f;
  unsigned r = v.u + 0x7FFFu + ((v.u >> 16) & 1u);
  return (u16)(r >> 16);
}
__device__ __forceinline__ float b2f(u16 h){
  union { unsigned u; float f; } v; v.u = ((unsigned)h) << 16; return v.f;
}
__device__ __forceinline__ short8 pack8(fx4 a, fx4 b){
  short8 v;
  v[0]=(short)f2b(a[0]); v[1]=(short)f2b(a[1]); v[2]=(short)f2b(a[2]); v[3]=(short)f2b(a[3]);
  v[4]=(short)f2b(b[0]); v[5]=(short)f2b(b[1]); v[6]=(short)f2b(b[2]); v[7]=(short)f2b(b[3]);
  return v;
}
__device__ __forceinline__ void gload16(const void* g, void* l){
  __builtin_amdgcn_global_load_lds(
    (const __attribute__((address_space(1))) uint32_t*)g,
    (__attribute__((address_space(3))) uint32_t*)l, 16, 0, 0);
}
__device__ __forceinline__ void bar(){
  asm volatile("" ::: "memory");
  __builtin_amdgcn_s_barrier();
  asm volatile("" ::: "memory");
}

// ---------- LDS swizzle helper (T2: byte ^= (row&7)<<4) ----------
__device__ __forceinline__ const short8* ldsRd(const u16* base, int rowBytes, int row, int colElem){
  unsigned byte = (unsigned)(row * rowBytes + colElem * 2);
  byte ^= (unsigned)((row & 7) << 4);
  return (const short8*)((const char*)base + byte);
}
__device__ __forceinline__ u16* psPtr(u16* base, int w, int row, int colElem){
  unsigned byte = (unsigned)(row * 128 + colElem * 2);
  byte ^= (unsigned)((row & 7) << 4);
  return (u16*)((char*)base + w * 2048 + byte);
}

// ================= aux bodies (vectorized short8 stores) =================
__device__ __forceinline__ void f2b8_body(const float* __restrict__ src, u16* __restrict__ dst, int bid){
  size_t i = ((size_t)bid * 256 + threadIdx.x) * 8;
  *(short8*)(dst + i) = pack8(*(const fx4*)(src + i), *(const fx4*)(src + i + 4));
}

__device__ __forceinline__ void xcat_body(const float* __restrict__ x, const float* __restrict__ ad,
                                          u16* __restrict__ dst, int bid){
  size_t i = ((size_t)bid * 256 + threadIdx.x) * 8;
  int row = (int)(i >> 12), col = (int)(i & 4095);
  short8 v = {0,0,0,0,0,0,0,0};
  const float* s = nullptr;
  if (row < 4096) s = x + i;
  else if (row < 4096 + Bz*ALz) s = ad + (size_t)(row - 4096) * 4096 + col;
  if (s) v = pack8(*(const fx4*)s, *(const fx4*)(s + 4));
  *(short8*)(dst + i) = v;
}

__device__ __forceinline__ void l1cat_body(const float* __restrict__ a, const float* __restrict__ b,
                                           const float* __restrict__ c, u16* __restrict__ dst, int bid){
  size_t i = ((size_t)bid * 256 + threadIdx.x) * 8;
  int row = (int)(i >> 12), col = (int)(i & 4095);
  short8 v = {0,0,0,0,0,0,0,0};
  const float* s = nullptr;
  if (row < 16) s = a + i;
  else if (row < 32) s = b + (size_t)(row - 16) * 4096 + col;
  else if (row < 48) s = c + (size_t)(row - 32) * 4096 + col;
  if (s) v = pack8(*(const fx4*)s, *(const fx4*)(s + 4));
  *(short8*)(dst + i) = v;
}

__device__ __forceinline__ void lo1pad_body(const float* __restrict__ src, u16* __restrict__ dst, int bid){
  size_t i = ((size_t)bid * 256 + threadIdx.x) * 8;
  int row = (int)(i >> 12);
  short8 v = {0,0,0,0,0,0,0,0};
  if (row < 16) v = pack8(*(const fx4*)(src + i), *(const fx4*)(src + i + 4));
  *(short8*)(dst + i) = v;
}

// split-K LoRA-l1 GEMM body (128^2 tile, K-slice 512) — writes f32 partials
__device__ __forceinline__ void gemm_lora_body(u16* shA, u16* shB,
    const u16* __restrict__ A, const u16* __restrict__ Bm, float* __restrict__ Cpart,
    int K, int bid2){
  const int tid = threadIdx.x;
  const int w = tid >> 6, l = tid & 63;
  const int lrow = l & 15, lgrp = l >> 4;
  const int ks = bid2 & 7;
  const int bm = (bid2 >> 3) * 128;
  const int wr = (w >> 1) * 64, wc = (w & 1) * 64;

  const fx4 fz = {0.f, 0.f, 0.f, 0.f};
  fx4 acc[4][4];
#pragma unroll
  for (int i = 0; i < 4; i++)
#pragma unroll
    for (int j = 0; j < 4; j++) acc[i][j] = fz;

  const u16* Abase = A + (size_t)bm * K;
  const int kbeg = ks * 512, kend = kbeg + 512;

  for (int k0 = kbeg; k0 < kend; k0 += 64){
    __syncthreads();
#pragma unroll
    for (int i = 0; i < 4; i++){
      int c = i * 256 + tid;
      int row = c >> 3, cs = c & 7;
      int off = (cs ^ (row & 7)) << 3;
      gload16(Abase + (size_t)row * K + k0 + off, shA + c * 8);
      gload16(Bm + (size_t)row * K + k0 + off, shB + c * 8);
    }
    __syncthreads();
#pragma unroll
    for (int kk = 0; kk < 2; kk++){
      short8 a[4], b[4];
#pragma unroll
      for (int i = 0; i < 4; i++) a[i] = *ldsRd(shA, 128, wr + i*16 + lrow, kk*32 + lgrp*8);
#pragma unroll
      for (int j = 0; j < 4; j++) b[j] = *ldsRd(shB, 128, wc + j*16 + lrow, kk*32 + lgrp*8);
#pragma unroll
      for (int i = 0; i < 4; i++)
#pragma unroll
        for (int j = 0; j < 4; j++)
          acc[i][j] = __builtin_amdgcn_mfma_f32_16x16x32_bf16(a[i], b[j], acc[i][j], 0, 0, 0);
    }
  }

  float* C = Cpart + (size_t)ks * 4096 * 128;
#pragma unroll
  for (int i = 0; i < 4; i++)
#pragma unroll
    for (int r = 0; r < 4; r++){
      int gm = bm + wr + i*16 + lgrp*4 + r;
      float* crow = C + (size_t)gm * 128 + wc + lrow;
#pragma unroll
      for (int j = 0; j < 4; j++) crow[j*16] = acc[i][j][r];
    }
}

// thin adapter GEMM body reading f32 weights (Wb-independent)
__device__ __forceinline__ void adgemm_f32_body(const u16* __restrict__ A, const float* __restrict__ Bw,
    u16* __restrict__ C, int N, int K, int bid){
  const int tid = threadIdx.x;
  const int w = tid >> 6, l = tid & 63;
  const int lrow = l & 15, lgrp = l >> 4;
  const int n0 = bid * 64 + w * 16;

  const fx4 fz = {0.f, 0.f, 0.f, 0.f};
  fx4 acc[3];
#pragma unroll
  for (int i = 0; i < 3; i++) acc[i] = fz;

  const float* Brow = Bw + (size_t)(n0 + lrow) * K + lgrp * 8;
  const u16* Arow = A + (size_t)lrow * K + lgrp * 8;
  for (int k0 = 0; k0 < K; k0 += 32){
    fx4 b0 = *(const fx4*)(Brow + k0);
    fx4 b1 = *(const fx4*)(Brow + k0 + 4);
    short8 b = pack8(b0, b1);
#pragma unroll
    for (int mf = 0; mf < 3; mf++){
      short8 a = *(const short8*)(Arow + (size_t)mf * 16 * K + k0);
      acc[mf] = __builtin_amdgcn_mfma_f32_16x16x32_bf16(a, b, acc[mf], 0, 0, 0);
    }
  }
#pragma unroll
  for (int mf = 0; mf < 3; mf++)
#pragma unroll
    for (int r = 0; r < 4; r++)
      C[(size_t)(mf * 16 + lgrp * 4 + r) * N + n0 + lrow] = f2b(acc[mf][r]);
}

// fused LoRA-add + RoPE (+reshape to B,H,S,HD), 16 elems/thread, short8 stores
__device__ __forceinline__ void lorarope_body(const u16* __restrict__ xin, const float* __restrict__ tp,
    const float* __restrict__ l2, const float* __restrict__ fcos, const float* __restrict__ fsin,
    u16* __restrict__ outp, int roff, float* ts, int m){
  const int tid = threadIdx.x;
  const int b = m >> 10, s = m & 1023;
  if (tid < 16){
    float a = 0.f;
#pragma unroll
    for (int p = 0; p < 8; p++) a += tp[((size_t)p * 4096 + m) * 128 + roff + tid];
    ts[tid] = a;
  }
  __syncthreads();
  float tsr[16];
#pragma unroll
  for (int r = 0; r < 16; r++) tsr[r] = ts[r];

  const int e0 = tid * 16;
  const int h = e0 >> 7, dd = e0 & 127;
  short8 x0 = *(const short8*)&xin[(size_t)m * 4096 + e0];
  short8 x1 = *(const short8*)&xin[(size_t)m * 4096 + e0 + 8];
  float v[16];
#pragma unroll
  for (int i = 0; i < 16; i++){
    int o = e0 + i;
    const fx4* lv = (const fx4*)(l2 + (size_t)o * 16);
    float ss = 0.f;
#pragma unroll
    for (int q = 0; q < 4; q++){
      fx4 lq = lv[q];
      ss += tsr[q*4]*lq[0] + tsr[q*4+1]*lq[1] + tsr[q*4+2]*lq[2] + tsr[q*4+3]*lq[3];
    }
    u16 raw = (i < 8) ? (u16)x0[i] : (u16)x1[i - 8];
    v[i] = b2f(raw) + ss;
  }
  short8 o0, o1;
#pragma unroll
  for (int i = 0; i < 16; i += 2){
    int j = (dd + i) >> 1;
    float c = fcos[s * 64 + j], sn = fsin[s * 64 + j];
    float re = v[i] * c - v[i+1] * sn;
    float im = v[i] * sn + v[i+1] * c;
    if (i < 8){ o0[i] = (short)f2b(re); o0[i+1] = (short)f2b(im); }
    else      { o1[i-8] = (short)f2b(re); o1[i-7] = (short)f2b(im); }
  }
  size_t oi = (((size_t)(b * Hz + h)) * Sz + s) * HDz + dd;
  *(short8*)&outp[oi] = o0;
  *(short8*)&outp[oi + 8] = o1;
}

// fused LoRA-add in place (v path), 16 elems/thread
__device__ __forceinline__ void loraadd16_body(u16* __restrict__ y, const float* __restrict__ tp,
    const float* __restrict__ l2, int roff, float* ts, int m){
  const int tid = threadIdx.x;
  if (tid < 16){
    float a = 0.f;
#pragma unroll
    for (int p = 0; p < 8; p++) a += tp[((size_t)p * 4096 + m) * 128 + roff + tid];
    ts[tid] = a;
  }
  __syncthreads();
  float tsr[16];
#pragma unroll
  for (int r = 0; r < 16; r++) tsr[r] = ts[r];

  const int e0 = tid * 16;
  short8 x0 = *(const short8*)&y[(size_t)m * 4096 + e0];
  short8 x1 = *(const short8*)&y[(size_t)m * 4096 + e0 + 8];
  short8 o0, o1;
#pragma unroll
  for (int i = 0; i < 16; i++){
    int o = e0 + i;
    const fx4* lv = (const fx4*)(l2 + (size_t)o * 16);
    float ss = 0.f;
#pragma unroll
    for (int q = 0; q < 4; q++){
      fx4 lq = lv[q];
      ss += tsr[q*4]*lq[0] + tsr[q*4+1]*lq[1] + tsr[q*4+2]*lq[2] + tsr[q*4+3]*lq[3];
    }
    u16 raw = (i < 8) ? (u16)x0[i] : (u16)x1[i - 8];
    u16 nv = f2b(b2f(raw) + ss);
    if (i < 8) o0[i] = (short)nv; else o1[i-8] = (short)nv;
  }
  *(short8*)&y[(size_t)m * 4096 + e0] = o0;
  *(short8*)&y[(size_t)m * 4096 + e0 + 8] = o1;
}

__device__ __forceinline__ void adresh_body(const u16* __restrict__ akf, const u16* __restrict__ avf,
    u16* __restrict__ AK, u16* __restrict__ AVt, int bh){
  const int b = bh >> 5, h = bh & 31;
  const int tid = threadIdx.x;
#pragma unroll
  for (int i = 0; i < 8; i++){
    int e = i * 256 + tid;
    int jj = e >> 7, d = e & 127;
    u16 v = (jj < ALz) ? akf[(size_t)(b * ALz + jj) * DIMz + h * HDz + d] : (u16)0;
    AK[((size_t)bh * 16 + jj) * HDz + d] = v;
  }
#pragma unroll
  for (int i = 0; i < 16; i++){
    int e = i * 256 + tid;
    int d = e >> 5, jj = e & 31;
    u16 v = (jj < ALz) ? avf[(size_t)(b * ALz + jj) * DIMz + h * HDz + d] : (u16)0;
    AVt[((size_t)bh * HDz + d) * 32 + jj] = v;
  }
}

// ================= combo kernels (block-range dispatch) =================
__global__ __launch_bounds__(256)
void k_combo1(const float* x, const float* ad, u16* Xcat,
              const float* lq1, const float* lk1, const float* lv1, u16* l1b){
  int bid = blockIdx.x;
  if (bid < 8704) xcat_body(x, ad, Xcat, bid);
  else l1cat_body(lq1, lk1, lv1, l1b, bid - 8704);
}

__global__ __launch_bounds__(256)
void k_combo2(const float* wq, u16* Wb,
              const u16* Xcat, const u16* l1b, float* tpart,
              const u16* Xad, const float* wk, const float* wv, u16* xkad, u16* xvad){
  __shared__ __align__(16) u16 sh[2][128][64];
  int bid = blockIdx.x;
  if (bid < 8192) f2b8_body(wq, Wb, bid);
  else if (bid < 8448) gemm_lora_body(&sh[0][0][0], &sh[1][0][0], Xcat, l1b, tpart, 4096, bid - 8192);
  else if (bid < 8512) adgemm_f32_body(Xad, wk, xkad, 4096, 4096, bid - 8448);
  else adgemm_f32_body(Xad, wv, xvad, 4096, 4096, bid - 8512);
}

// f2b(wk) + adapter reshape (xkad/xvad ready since combo2)
__global__ __launch_bounds__(256)
void k_combo3(const float* wk, u16* Wb,
              const u16* xkad, const u16* xvad, u16* AK, u16* AVt){
  int bid = blockIdx.x;
  if (bid < 8192) f2b8_body(wk, Wb, bid);
  else adresh_body(xkad, xvad, AK, AVt, bid - 8192);
}

// f2b(wv) alone
__global__ __launch_bounds__(256)
void k_f2bw(const float* w, u16* Wb){ f2b8_body(w, Wb, blockIdx.x); }

// all three LoRA finishers AFTER V projection (Qb aliases Xcat, Kb aliases Wb — both dead now)
__global__ __launch_bounds__(256)
void k_combo5(const u16* xq, const u16* xk, u16* xv, const float* tpart,
              const float* lq2, const float* lk2, const float* lv2,
              const float* fcos, const float* fsin, u16* Qb, u16* Kb){
  __shared__ float ts[16];
  int bid = blockIdx.x;
  if (bid < 4096) lorarope_body(xq, tpart, lq2, fcos, fsin, Qb, 0, ts, bid);
  else if (bid < 8192) lorarope_body(xk, tpart, lk2, fcos, fsin, Kb, 16, ts, bid - 4096);
  else loraadd16_body(xv, tpart, lv2, 32, ts, bid - 8192);
}

__global__ __launch_bounds__(256)
void k_combo7(const float* wo, u16* Wb, const float* lo1, u16* l1b){
  int bid = blockIdx.x;
  if (bid < 8192) f2b8_body(wo, Wb, bid);
  else lo1pad_body(lo1, l1b, bid - 8192);
}

__global__ __launch_bounds__(256)
void k_gemm_lora(const u16* A, const u16* Bm, float* Cpart, int K){
  __shared__ __align__(16) u16 sh[2][128][64];
  gemm_lora_body(&sh[0][0][0], &sh[1][0][0], A, Bm, Cpart, K, blockIdx.x);
}

// final LoRA add into f32 output, 16 elems/thread via fx4 RMW
__global__ __launch_bounds__(256)
void k_loraaddf(float* __restrict__ y, const float* __restrict__ tp, const float* __restrict__ l2){
  __shared__ float ts[16];
  const int m = blockIdx.x;
  const int tid = threadIdx.x;
  if (tid < 16){
    float a = 0.f;
#pragma unroll
    for (int p = 0; p < 8; p++) a += tp[((size_t)p * 4096 + m) * 128 + tid];
    ts[tid] = a;
  }
  __syncthreads();
  float tsr[16];
#pragma unroll
  for (int r = 0; r < 16; r++) tsr[r] = ts[r];
  const int e0 = tid * 16;
  float* yp = y + (size_t)m * 4096 + e0;
#pragma unroll
  for (int q4 = 0; q4 < 4; q4++){
    fx4 cur = *(fx4*)(yp + q4 * 4);
#pragma unroll
    for (int ii = 0; ii < 4; ii++){
      int o = e0 + q4 * 4 + ii;
      const fx4* lv = (const fx4*)(l2 + (size_t)o * 16);
      float ss = 0.f;
#pragma unroll
      for (int q = 0; q < 4; q++){
        fx4 lq = lv[q];
        ss += tsr[q*4]*lq[0] + tsr[q*4+1]*lq[1] + tsr[q*4+2]*lq[2] + tsr[q*4+3]*lq[3];
      }
      cur[ii] += ss;
    }
    *(fx4*)(yp + q4 * 4) = cur;
  }
}

// ---------- V: (B,S,H,HD) -> Vt (B,H,HD,S) ----------
__global__ __launch_bounds__(256)
void k_vtrans(const u16* __restrict__ x, u16* __restrict__ vt){
  __shared__ __align__(16) u16 tile[64][128];
  int bid = blockIdx.x;
  int bh = bid >> 4;
  int b = bh >> 5, h = bh & 31;
  int s0 = (bid & 15) * 64;
  int tid = threadIdx.x;
#pragma unroll
  for (int i = 0; i < 4; i++){
    int c = i * 256 + tid;
    int ss = c >> 4, d8 = (c & 15) << 3;
    *(short8*)&tile[ss][d8] =
      *(const short8*)&x[(size_t)(b * Sz + s0 + ss) * DIMz + h * HDz + d8];
  }
  __syncthreads();
#pragma unroll
  for (int i = 0; i < 4; i++){
    int c = i * 256 + tid;
    int d = c >> 3, s8 = (c & 7) << 3;
    short8 v;
#pragma unroll
    for (int k = 0; k < 8; k++) v[k] = (short)tile[s8 + k][d];
    *(short8*)&vt[((size_t)bh * HDz + d) * Sz + s0 + s8] = v;
  }
}

// ---------- 256x256 8-phase counted-vmcnt NT bf16 GEMM ----------
#define PHASE(BUF, P, STAGE_STMT, VM_STMT)                                          \
  {                                                                                 \
    if ((P) == 0){                                                                  \
      _Pragma("unroll")                                                             \
      for (int nj = 0; nj < 4; nj++)                                                \
        _Pragma("unroll")                                                           \
        for (int kk = 0; kk < 2; kk++)                                              \
          bf[nj][kk] = *ldsRd(&lds[BUF][2 + (wn >> 1)][0][0], 128,                  \
                              (wn & 1) * 64 + nj * 16 + lrow, kk * 32 + lgrp * 8);  \
    }                                                                               \
    short8 af[2][2];                                                                \
    _Pragma("unroll")                                                               \
    for (int m2 = 0; m2 < 2; m2++)                                                  \
      _Pragma("unroll")                                                             \
      for (int kk = 0; kk < 2; kk++)                                                \
        af[m2][kk] = *ldsRd(&lds[BUF][wm][0][0], 128,                               \
                            ((P) * 2 + m2) * 16 + lrow, kk * 32 + lgrp * 8);        \
    STAGE_STMT;                                                                     \
    bar();                                                                          \
    __builtin_amdgcn_s_setprio(1);                                                  \
    _Pragma("unroll")                                                               \
    for (int m2 = 0; m2 < 2; m2++)                                                  \
      _Pragma("unroll")                                                             \
      for (int nj = 0; nj < 4; nj++)                                                \
        _Pragma("unroll")                                                           \
        for (int kk = 0; kk < 2; kk++)                                              \
          acc[(P) * 2 + m2][nj] = __builtin_amdgcn_mfma_f32_16x16x32_bf16(          \
              af[m2][kk], bf[nj][kk], acc[(P) * 2 + m2][nj], 0, 0, 0);              \
    __builtin_amdgcn_s_setprio(0);                                                  \
    VM_STMT;                                                                        \
    bar();                                                                          \
  }

__global__ __launch_bounds__(512, 2)
void gemm_nt256(const u16* __restrict__ A, const u16* __restrict__ Bm,
                void* __restrict__ Cp, int N, int K, int outBf16, int nbx){
  __shared__ __align__(16) u16 lds[2][4][128][64];
  const int tid = threadIdx.x;
  const int l = tid & 63, w = tid >> 6;
  const int lrow = l & 15, lgrp = l >> 4;
  const int wm = w >> 2, wn = w & 3;

  const int nwg = gridDim.x;
  const int cpx = nwg >> 3;
  const int swz = (blockIdx.x & 7) * cpx + (blockIdx.x >> 3);
  const int by = swz / nbx, bx = swz - by * nbx;
  const int bm = by << 8, bn = bx << 8;

  const u16* A0s = A  + (size_t)bm * K;
  const u16* A1s = A0s + (size_t)128 * K;
  const u16* B0s = Bm + (size_t)bn * K;
  const u16* B1s = B0s + (size_t)128 * K;
  const int nt = K >> 6;

  const fx4 fz = {0.f, 0.f, 0.f, 0.f};
  fx4 acc[8][4];
#pragma unroll
  for (int i = 0; i < 8; i++)
#pragma unroll
    for (int j = 0; j < 4; j++) acc[i][j] = fz;

  auto STAGEH = [&](int buf, int reg, const u16* src, int t){
#pragma unroll
    for (int r = 0; r < 2; r++){
      int c = r * 512 + tid;
      int row = c >> 3, cs = c & 7;
      int off = (cs ^ (row & 7)) << 3;
      gload16(src + (size_t)row * K + t * 64 + off, &lds[buf][reg][0][0] + c * 8);
    }
  };

  STAGEH(0, 0, A0s, 0); STAGEH(0, 1, A1s, 0);
  STAGEH(0, 2, B0s, 0); STAGEH(0, 3, B1s, 0);
  STAGEH(1, 2, B0s, 1); STAGEH(1, 3, B1s, 1);
  asm volatile("s_waitcnt vmcnt(4)" ::: "memory");
  bar();

  short8 bf[4][2];
  const int ni = nt >> 1;
  for (int i = 0; i < ni; i++){
    const int t0 = 2 * i, t1 = 2 * i + 1;
    const bool more = (i < ni - 1);
    PHASE(0, 0, { STAGEH(1, 0, A0s, t1); }, {});
    PHASE(0, 1, { STAGEH(1, 1, A1s, t1); }, {});
    PHASE(0, 2, { if (more) STAGEH(0, 2, B0s, t0 + 2); }, {});
    PHASE(0, 3, { if (more) STAGEH(0, 3, B1s, t0 + 2); },
          { if (more) { asm volatile("s_waitcnt vmcnt(4)" ::: "memory"); }
            else      { asm volatile("s_waitcnt vmcnt(0)" ::: "memory"); } });
    PHASE(1, 0, { if (more) STAGEH(0, 0, A0s, t0 + 2); }, {});
    PHASE(1, 1, { if (more) STAGEH(0, 1, A1s, t0 + 2); }, {});
    PHASE(1, 2, { if (more) STAGEH(1, 2, B0s, t1 + 2); }, {});
    PHASE(1, 3, { if (more) STAGEH(1, 3, B1s, t1 + 2); },
          { if (more) { asm volatile("s_waitcnt vmcnt(4)" ::: "memory"); } });
  }

  if (outBf16){
    u16* C = (u16*)Cp;
#pragma unroll
    for (int mi = 0; mi < 8; mi++)
#pragma unroll
      for (int r = 0; r < 4; r++){
        int gm = bm + wm * 128 + mi * 16 + lgrp * 4 + r;
        u16* crow = C + (size_t)gm * N + bn + wn * 64 + lrow;
#pragma unroll
        for (int nj = 0; nj < 4; nj++) crow[nj * 16] = f2b(acc[mi][nj][r]);
      }
  } else {
    float* C = (float*)Cp;
#pragma unroll
    for (int mi = 0; mi < 8; mi++)
#pragma unroll
      for (int r = 0; r < 4; r++){
        int gm = bm + wm * 128 + mi * 16 + lgrp * 4 + r;
        float* crow = C + (size_t)gm * N + bn + wn * 64 + lrow;
#pragma unroll
        for (int nj = 0; nj < 4; nj++) crow[nj * 16] = acc[mi][nj][r];
      }
  }
}

// ---------- flash attention + gated adapter attention ----------
__global__ __launch_bounds__(512)
void k_attn(const u16* __restrict__ Q, const u16* __restrict__ Kg,
            const u16* __restrict__ Vt, const u16* __restrict__ AKg,
            const u16* __restrict__ AVg, const float* __restrict__ gate,
            u16* __restrict__ outp){
  __shared__ __align__(16) u16 Ks[2][64][128];
  __shared__ __align__(16) u16 Vs[2][128][64];
  __shared__ __align__(16) u16 Ps[8][16][64];

  const int blk = blockIdx.x;
  const int jj = blk >> 3;
  const int bh = (blk & 7) * 16 + (jj & 15);
  const int bx = jj >> 4;
  const int b = bh >> 5, h = bh & 31;
  const int q0 = bx * 128;
  const int tid = threadIdx.x;
  const int w = tid >> 6, l = tid & 63;
  const int lrow = l & 15, lgrp = l >> 4;

  const u16* Qb = Q  + (size_t)bh * (Sz * HDz) + (size_t)q0 * HDz;
  const u16* Kb = Kg + (size_t)bh * (Sz * HDz);
  const u16* Vb = Vt + (size_t)bh * (HDz * Sz);
  u16* PsB = &Ps[0][0][0];

  short8 aq[4];
#pragma unroll
  for (int kk = 0; kk < 4; kk++)
    aq[kk] = *(const short8*)&Qb[(size_t)(w*16 + lrow) * HDz + kk*32 + lgrp*8];

  const fx4 fz = {0.f, 0.f, 0.f, 0.f};
  fx4 o[8];
#pragma unroll
  for (int i = 0; i < 8; i++) o[i] = fz;
  float mrow[4], lsum[4];
#pragma unroll
  for (int r = 0; r < 4; r++){ mrow[r] = -1e30f; lsum[r] = 0.f; }

  const float scale2 = 0.088388347648318447f * 1.4426950408889634f;
  const int qwbase = q0 + w * 16;
  const int qrowbase = qwbase + lgrp * 4;
  const int ktiles = 2 * bx + 2;

  auto STAGE = [&](int buf, int kt){
    const int k0 = kt * 64;
#pragma unroll
    for (int r = 0; r < 2; r++){
      int c = r * 512 + tid;
      int row = c >> 4, cs = c & 15;
      int gcs = cs ^ (row & 7);
      gload16(Kb + (size_t)(k0 + row) * HDz + gcs * 8, ((u16*)&Ks[buf][0][0]) + c * 8);
    }
#pragma unroll
    for (int r = 0; r < 2; r++){
      int c = r * 512 + tid;
      int row = c >> 3, cs = c & 7;
      int gcs = cs ^ (row & 7);
      gload16(Vb + (size_t)row * Sz + k0 + gcs * 8, ((u16*)&Vs[buf][0][0]) + c * 8);
    }
  };

  STAGE(0, 0);
  asm volatile("s_waitcnt vmcnt(0)" ::: "memory");
  bar();

  for (int kt = 0; kt < ktiles; kt++){
    const int cur = kt & 1;
    if (kt + 1 < ktiles) STAGE(cur ^ 1, kt + 1);
    const int k0 = kt * 64;

    if (k0 <= qwbase + 15){
      fx4 sc[4];
#pragma unroll
      for (int j = 0; j < 4; j++) sc[j] = fz;
      __builtin_amdgcn_s_setprio(1);
#pragma unroll
      for (int kk = 0; kk < 4; kk++){
#pragma unroll
        for (int j = 0; j < 4; j++){
          short8 bk = *ldsRd(&Ks[cur][0][0], 256, j*16 + lrow, kk*32 + lgrp*8);
          sc[j] = __builtin_amdgcn_mfma_f32_16x16x32_bf16(aq[kk], bk, sc[j], 0, 0, 0);
        }
      }
      __builtin_amdgcn_s_setprio(0);
      const bool domask = (k0 + 63 > qwbase);
      float tm[4];
#pragma unroll
      for (int r = 0; r < 4; r++){
        float mx = -1e30f;
#pragma unroll
        for (int j = 0; j < 4; j++){
          float v = sc[j][r] * scale2;
          if (domask){
            int kcol = k0 + j*16 + lrow;
            if (kcol > qrowbase + r) v = -1e30f;
          }
          sc[j][r] = v;
          mx = fmaxf(mx, v);
        }
#pragma unroll
        for (int d = 1; d < 16; d <<= 1) mx = fmaxf(mx, __shfl_xor(mx, d));
        tm[r] = mx;
      }
      if (!__all(tm[0] <= mrow[0] + 11.5f && tm[1] <= mrow[1] + 11.5f &&
                 tm[2] <= mrow[2] + 11.5f && tm[3] <= mrow[3] + 11.5f)){
        float esc[4];
#pragma unroll
        for (int r = 0; r < 4; r++){
          float nm = fmaxf(mrow[r], tm[r]);
          esc[r] = exp2f(mrow[r] - nm);
          mrow[r] = nm;
          lsum[r] *= esc[r];
        }
#pragma unroll
        for (int j = 0; j < 8; j++)
#pragma unroll
          for (int r = 0; r < 4; r++) o[j][r] *= esc[r];
      }
#pragma unroll
      for (int r = 0; r < 4; r++){
        float s = 0.f;
#pragma unroll
        for (int j = 0; j < 4; j++){
          float p = exp2f(sc[j][r] - mrow[r]);
          sc[j][r] = p;
          s += p;
        }
#pragma unroll
        for (int d = 1; d < 16; d <<= 1) s += __shfl_xor(s, d);
        lsum[r] += s;
      }
#pragma unroll
      for (int j = 0; j < 4; j++)
#pragma unroll
        for (int r = 0; r < 4; r++)
          *psPtr(PsB, w, lgrp*4 + r, j*16 + lrow) = f2b(sc[j][r]);
      __builtin_amdgcn_s_setprio(1);
#pragma unroll
      for (int kk = 0; kk < 2; kk++){
        short8 ap = *(const short8*)psPtr(PsB, w, lrow, kk*32 + lgrp*8);
#pragma unroll
        for (int j = 0; j < 8; j++){
          short8 bv = *ldsRd(&Vs[cur][0][0], 128, j*16 + lrow, kk*32 + lgrp*8);
          o[j] = __builtin_amdgcn_mfma_f32_16x16x32_bf16(ap, bv, o[j], 0, 0, 0);
        }
      }
      __builtin_amdgcn_s_setprio(0);
    }

    asm volatile("s_waitcnt vmcnt(0)" ::: "memory");
    bar();
  }

#pragma unroll
  for (int j = 0; j < 8; j++)
#pragma unroll
    for (int r = 0; r < 4; r++) o[j][r] /= lsum[r];

  fx4 s2 = fz;
  const u16* AKb = AKg + (size_t)bh * (16 * HDz);
#pragma unroll
  for (int kk = 0; kk < 4; kk++){
    short8 bk = *(const short8*)&AKb[(size_t)lrow * HDz + kk*32 + lgrp*8];
    s2 = __builtin_amdgcn_mfma_f32_16x16x32_bf16(aq[kk], bk, s2, 0, 0, 0);
  }
  const float g = tanhf(gate[h]);
#pragma unroll
  for (int r = 0; r < 4; r++){
    float v = s2[r] * scale2;
    if (lrow >= ALz) v = -1e30f;
    float mx = v;
#pragma unroll
    for (int d = 1; d < 16; d <<= 1) mx = fmaxf(mx, __shfl_xor(mx, d));
    float p = exp2f(v - mx);
    float s = p;
#pragma unroll
    for (int d = 1; d < 16; d <<= 1) s += __shfl_xor(s, d);
    float p2 = g * p / s;
    *psPtr(PsB, w, lgrp*4 + r, lrow) = f2b(p2);
    *psPtr(PsB, w, lgrp*4 + r, 16 + lrow) = 0;
  }
  {
    const u16* AVb = AVg + (size_t)bh * (HDz * 32);
    short8 ap = *(const short8*)psPtr(PsB, w, lrow, lgrp*8);
#pragma unroll
    for (int j = 0; j < 8; j++){
      short8 bv = *(const short8*)&AVb[(size_t)(j*16 + lrow) * 32 + lgrp*8];
      o[j] = __builtin_amdgcn_mfma_f32_16x16x32_bf16(ap, bv, o[j], 0, 0, 0);
    }
  }

  // vectorized output: two 64-col halves restaged through Ps[w] (per-wave, no barrier)
  u16* ob = outp + (size_t)(b * Sz + q0 + w * 16) * DIMz + h * HDz;
  const int rr = l >> 2, cc = (l & 3) * 16;
#pragma unroll
  for (int half = 0; half < 2; half++){
#pragma unroll
    for (int j = 0; j < 4; j++)
#pragma unroll
      for (int r = 0; r < 4; r++)
        Ps[w][lgrp*4 + r][j*16 + lrow] = f2b(o[half*4 + j][r]);
    short8 s0 = *(const short8*)&Ps[w][rr][cc];
    short8 s1 = *(const short8*)&Ps[w][rr][cc + 8];
    *(short8*)&ob[(size_t)rr * DIMz + half*64 + cc] = s0;
    *(short8*)&ob[(size_t)rr * DIMz + half*64 + cc + 8] = s1;
  }
}

// ---------- host ----------
extern "C" void kernel_launch(void* const* d_in, const int* in_sizes, int n_in,
                              void* d_out, int out_size, void* d_ws, size_t ws_size,
                              hipStream_t stream){
  const float* x    = (const float*)d_in[0];
  const float* adap = (const float*)d_in[1];
  const float* wq   = (const float*)d_in[2];
  const float* wk   = (const float*)d_in[3];
  const float* wv   = (const float*)d_in[4];
  const float* wo   = (const float*)d_in[5];
  const float* lq1  = (const float*)d_in[6];
  const float* lq2  = (const float*)d_in[7];
  const float* lk1  = (const float*)d_in[8];
  const float* lk2  = (const float*)d_in[9];
  const float* lv1  = (const float*)d_in[10];
  const float* lv2  = (const float*)d_in[11];
  const float* lo1  = (const float*)d_in[12];
  const float* lo2  = (const float*)d_in[13];
  const float* gate = (const float*)d_in[14];
  const float* fcos = (const float*)d_in[15];
  const float* fsin = (const float*)d_in[16];

  const size_t MB = 1024 * 1024;
  char* ws = (char*)d_ws;
  u16*  Xcat = (u16*)(ws);                 // 4352x4096 bf16 (34 MB); later Q
  u16*  Wb   = (u16*)(ws + 34 * MB);       // 32 MB; later K
  u16*  xq   = (u16*)(ws + 66 * MB);       // 34 MB; later attn_out
  u16*  xk   = (u16*)(ws + 100 * MB);      // 34 MB
  u16*  xv   = (u16*)(ws + 134 * MB);      // 34 MB
  u16*  Vt   = (u16*)(ws + 168 * MB);      // 32 MB; tpart (16 MB f32) aliases (disjoint lifetimes)
  float* tpart = (float*)(ws + 168 * MB);  // [8][4096][128] f32
  u16*  l1b  = (u16*)(ws + 200 * MB);      // 1 MB
  u16*  AKb  = (u16*)(ws + 201 * MB);      // 0.5 MB
  u16*  AVb  = (u16*)(ws + 201 * MB + 512 * 1024); // 1 MB
  u16*  Qb = Xcat;
  u16*  Kb = Wb;
  u16*  attn = xq;
  float* out = (float*)d_out;

  dim3 blk(256);
  const u16* Xad = Xcat + (size_t)4096 * 4096;
  u16* xkad = xk + (size_t)4096 * 4096;
  u16* xvad = xv + (size_t)4096 * 4096;

  // 1: xcat + l1cat
  k_combo1<<<dim3(8960), blk, 0, stream>>>(x, adap, Xcat, lq1, lk1, lv1, l1b);
  // 2: f2b(wq) + split-K LoRA GEMM + adapter K/V GEMMs (read f32 weights)
  k_combo2<<<dim3(8576), blk, 0, stream>>>(wq, Wb, Xcat, l1b, tpart, Xad, wk, wv, xkad, xvad);
  // 3: Q projection
  gemm_nt256<<<dim3(256), dim3(512), 0, stream>>>(Xcat, Wb, xq, 4096, 4096, 1, 16);
  // 4: f2b(wk) + adapter reshape
  k_combo3<<<dim3(8320), blk, 0, stream>>>(wk, Wb, xkad, xvad, AKb, AVb);
  // 5: K projection
  gemm_nt256<<<dim3(256), dim3(512), 0, stream>>>(Xcat, Wb, xk, 4096, 4096, 1, 16);
  // 6: f2b(wv)
  k_f2bw<<<dim3(8192), blk, 0, stream>>>(wv, Wb);
  // 7: V projection (last reader of Xcat and of Wb=wv)
  gemm_nt256<<<dim3(256), dim3(512), 0, stream>>>(Xcat, Wb, xv, 4096, 4096, 1, 16);
  // 8: LoRA+RoPE q (xq->Qb=Xcat) + LoRA+RoPE k (xk->Kb=Wb) + LoRA add v (in place)
  k_combo5<<<dim3(12288), blk, 0, stream>>>(xq, xk, xv, tpart, lq2, lk2, lv2,
                                            fcos, fsin, Qb, Kb);
  // 9: V transpose (tpart consumed; Vt may overwrite it)
  k_vtrans<<<dim3(2048), blk, 0, stream>>>(xv, Vt);
  // 10: attention
  k_attn<<<dim3(1024), dim3(512), 0, stream>>>(Qb, Kb, Vt, AKb, AVb, gate, attn);
  // 11: f2b(wo) + lo1 pad
  k_combo7<<<dim3(8448), blk, 0, stream>>>(wo, Wb, lo1, l1b);
  // 12: output projection
  gemm_nt256<<<dim3(256), dim3(512), 0, stream>>>(attn, Wb, out, 4096, 4096, 0, 16);
  // 13: split-K LoRA GEMM on attn output
  k_gemm_lora<<<dim3(256), blk, 0, stream>>>(attn, l1b, tpart, 4096);
  // 14: final LoRA add into f32 output
  k_loraaddf<<<dim3(4096), blk, 0, stream>>>(out, tpart, lo2);
}

// Round 13
// 1276.439 us; speedup vs baseline: 1.1573x; 1.1573x over previous
//
#include <hip/hip_runtime.h>
#include <stdint.h>

#define Bz 4
#define Sz 1024
#define DIMz 4096
#define Hz 32
#define HDz 128
#define ALz 10

typedef unsigned short u16;
typedef __attribute__((ext_vector_type(8))) short short8;
typedef __attribute__((ext_vector_type(4))) float fx4;

__device__ __forceinline__ u16 f2b(float f){
  union { float f; unsigned u; } v; v.f = f;
  unsigned r = v.u + 0x7FFFu + ((v.u >> 16) & 1u);
  return (u16)(r >> 16);
}
__device__ __forceinline__ float b2f(u16 h){
  union { unsigned u; float f; } v; v.u = ((unsigned)h) << 16; return v.f;
}
__device__ __forceinline__ short8 pack8(fx4 a, fx4 b){
  short8 v;
  v[0]=(short)f2b(a[0]); v[1]=(short)f2b(a[1]); v[2]=(short)f2b(a[2]); v[3]=(short)f2b(a[3]);
  v[4]=(short)f2b(b[0]); v[5]=(short)f2b(b[1]); v[6]=(short)f2b(b[2]); v[7]=(short)f2b(b[3]);
  return v;
}
__device__ __forceinline__ void gload16(const void* g, void* l){
  __builtin_amdgcn_global_load_lds(
    (const __attribute__((address_space(1))) uint32_t*)g,
    (__attribute__((address_space(3))) uint32_t*)l, 16, 0, 0);
}
__device__ __forceinline__ void bar(){
  asm volatile("" ::: "memory");
  __builtin_amdgcn_s_barrier();
  asm volatile("" ::: "memory");
}

// ---------- LDS swizzle helper (T2: byte ^= (row&7)<<4) ----------
__device__ __forceinline__ const short8* ldsRd(const u16* base, int rowBytes, int row, int colElem){
  unsigned byte = (unsigned)(row * rowBytes + colElem * 2);
  byte ^= (unsigned)((row & 7) << 4);
  return (const short8*)((const char*)base + byte);
}
__device__ __forceinline__ u16* psPtr(u16* base, int w, int row, int colElem){
  unsigned byte = (unsigned)(row * 128 + colElem * 2);
  byte ^= (unsigned)((row & 7) << 4);
  return (u16*)((char*)base + w * 2048 + byte);
}

// ================= aux bodies =================
__device__ __forceinline__ void f2b8_body(const float* __restrict__ src, u16* __restrict__ dst, int bid){
  size_t i = ((size_t)bid * 256 + threadIdx.x) * 8;
  *(short8*)(dst + i) = pack8(*(const fx4*)(src + i), *(const fx4*)(src + i + 4));
}

__device__ __forceinline__ void xcat_body(const float* __restrict__ x, const float* __restrict__ ad,
                                          u16* __restrict__ dst, int bid){
  size_t i = ((size_t)bid * 256 + threadIdx.x) * 8;
  int row = (int)(i >> 12), col = (int)(i & 4095);
  short8 v = {0,0,0,0,0,0,0,0};
  const float* s = nullptr;
  if (row < 4096) s = x + i;
  else if (row < 4096 + Bz*ALz) s = ad + (size_t)(row - 4096) * 4096 + col;
  if (s) v = pack8(*(const fx4*)s, *(const fx4*)(s + 4));
  *(short8*)(dst + i) = v;
}

__device__ __forceinline__ void l1cat_body(const float* __restrict__ a, const float* __restrict__ b,
                                           const float* __restrict__ c, u16* __restrict__ dst, int bid){
  size_t i = ((size_t)bid * 256 + threadIdx.x) * 8;
  int row = (int)(i >> 12), col = (int)(i & 4095);
  short8 v = {0,0,0,0,0,0,0,0};
  const float* s = nullptr;
  if (row < 16) s = a + i;
  else if (row < 32) s = b + (size_t)(row - 16) * 4096 + col;
  else if (row < 48) s = c + (size_t)(row - 32) * 4096 + col;
  if (s) v = pack8(*(const fx4*)s, *(const fx4*)(s + 4));
  *(short8*)(dst + i) = v;
}

__device__ __forceinline__ void lo1pad_body(const float* __restrict__ src, u16* __restrict__ dst, int bid){
  size_t i = ((size_t)bid * 256 + threadIdx.x) * 8;
  int row = (int)(i >> 12);
  short8 v = {0,0,0,0,0,0,0,0};
  if (row < 16) v = pack8(*(const fx4*)(src + i), *(const fx4*)(src + i + 4));
  *(short8*)(dst + i) = v;
}

// split-K LoRA-l1 GEMM body (128^2 tile, K-slice 512) — writes f32 partials
__device__ __forceinline__ void gemm_lora_body(u16* shA, u16* shB,
    const u16* __restrict__ A, const u16* __restrict__ Bm, float* __restrict__ Cpart,
    int K, int bid2){
  const int tid = threadIdx.x;
  const int w = tid >> 6, l = tid & 63;
  const int lrow = l & 15, lgrp = l >> 4;
  const int ks = bid2 & 7;
  const int bm = (bid2 >> 3) * 128;
  const int wr = (w >> 1) * 64, wc = (w & 1) * 64;

  const fx4 fz = {0.f, 0.f, 0.f, 0.f};
  fx4 acc[4][4];
#pragma unroll
  for (int i = 0; i < 4; i++)
#pragma unroll
    for (int j = 0; j < 4; j++) acc[i][j] = fz;

  const u16* Abase = A + (size_t)bm * K;
  const int kbeg = ks * 512, kend = kbeg + 512;

  for (int k0 = kbeg; k0 < kend; k0 += 64){
    __syncthreads();
#pragma unroll
    for (int i = 0; i < 4; i++){
      int c = i * 256 + tid;
      int row = c >> 3, cs = c & 7;
      int off = (cs ^ (row & 7)) << 3;
      gload16(Abase + (size_t)row * K + k0 + off, shA + c * 8);
      gload16(Bm + (size_t)row * K + k0 + off, shB + c * 8);
    }
    __syncthreads();
#pragma unroll
    for (int kk = 0; kk < 2; kk++){
      short8 a[4], b[4];
#pragma unroll
      for (int i = 0; i < 4; i++) a[i] = *ldsRd(shA, 128, wr + i*16 + lrow, kk*32 + lgrp*8);
#pragma unroll
      for (int j = 0; j < 4; j++) b[j] = *ldsRd(shB, 128, wc + j*16 + lrow, kk*32 + lgrp*8);
#pragma unroll
      for (int i = 0; i < 4; i++)
#pragma unroll
        for (int j = 0; j < 4; j++)
          acc[i][j] = __builtin_amdgcn_mfma_f32_16x16x32_bf16(a[i], b[j], acc[i][j], 0, 0, 0);
    }
  }

  float* C = Cpart + (size_t)ks * 4096 * 128;
#pragma unroll
  for (int i = 0; i < 4; i++)
#pragma unroll
    for (int r = 0; r < 4; r++){
      int gm = bm + wr + i*16 + lgrp*4 + r;
      float* crow = C + (size_t)gm * 128 + wc + lrow;
#pragma unroll
      for (int j = 0; j < 4; j++) crow[j*16] = acc[i][j][r];
    }
}

// thin adapter GEMM body reading f32 weights (Wb-independent)
__device__ __forceinline__ void adgemm_f32_body(const u16* __restrict__ A, const float* __restrict__ Bw,
    u16* __restrict__ C, int N, int K, int bid){
  const int tid = threadIdx.x;
  const int w = tid >> 6, l = tid & 63;
  const int lrow = l & 15, lgrp = l >> 4;
  const int n0 = bid * 64 + w * 16;

  const fx4 fz = {0.f, 0.f, 0.f, 0.f};
  fx4 acc[3];
#pragma unroll
  for (int i = 0; i < 3; i++) acc[i] = fz;

  const float* Brow = Bw + (size_t)(n0 + lrow) * K + lgrp * 8;
  const u16* Arow = A + (size_t)lrow * K + lgrp * 8;
  for (int k0 = 0; k0 < K; k0 += 32){
    fx4 b0 = *(const fx4*)(Brow + k0);
    fx4 b1 = *(const fx4*)(Brow + k0 + 4);
    short8 b = pack8(b0, b1);
#pragma unroll
    for (int mf = 0; mf < 3; mf++){
      short8 a = *(const short8*)(Arow + (size_t)mf * 16 * K + k0);
      acc[mf] = __builtin_amdgcn_mfma_f32_16x16x32_bf16(a, b, acc[mf], 0, 0, 0);
    }
  }
#pragma unroll
  for (int mf = 0; mf < 3; mf++)
#pragma unroll
    for (int r = 0; r < 4; r++)
      C[(size_t)(mf * 16 + lgrp * 4 + r) * N + n0 + lrow] = f2b(acc[mf][r]);
}

__device__ __forceinline__ void adresh_body(const u16* __restrict__ akf, const u16* __restrict__ avf,
    u16* __restrict__ AK, u16* __restrict__ AVt, int bh){
  const int b = bh >> 5, h = bh & 31;
  const int tid = threadIdx.x;
#pragma unroll
  for (int i = 0; i < 8; i++){
    int e = i * 256 + tid;
    int jj = e >> 7, d = e & 127;
    u16 v = (jj < ALz) ? akf[(size_t)(b * ALz + jj) * DIMz + h * HDz + d] : (u16)0;
    AK[((size_t)bh * 16 + jj) * HDz + d] = v;
  }
#pragma unroll
  for (int i = 0; i < 16; i++){
    int e = i * 256 + tid;
    int d = e >> 5, jj = e & 31;
    u16 v = (jj < ALz) ? avf[(size_t)(b * ALz + jj) * DIMz + h * HDz + d] : (u16)0;
    AVt[((size_t)bh * HDz + d) * 32 + jj] = v;
  }
}

// ================= combo kernels =================
__global__ __launch_bounds__(256)
void k_combo1(const float* x, const float* ad, u16* Xcat,
              const float* lq1, const float* lk1, const float* lv1, u16* l1b){
  int bid = blockIdx.x;
  if (bid < 8704) xcat_body(x, ad, Xcat, bid);
  else l1cat_body(lq1, lk1, lv1, l1b, bid - 8704);
}

__global__ __launch_bounds__(256)
void k_combo2(const float* wq, u16* Wb,
              const u16* Xcat, const u16* l1b, float* tpart,
              const u16* Xad, const float* wk, const float* wv, u16* xkad, u16* xvad){
  __shared__ __align__(16) u16 sh[2][128][64];
  int bid = blockIdx.x;
  if (bid < 8192) f2b8_body(wq, Wb, bid);
  else if (bid < 8448) gemm_lora_body(&sh[0][0][0], &sh[1][0][0], Xcat, l1b, tpart, 4096, bid - 8192);
  else if (bid < 8512) adgemm_f32_body(Xad, wk, xkad, 4096, 4096, bid - 8448);
  else adgemm_f32_body(Xad, wv, xvad, 4096, 4096, bid - 8512);
}

// f2b(wk) + adapter reshape (xkad/xvad ready since combo2)
__global__ __launch_bounds__(256)
void k_combo3(const float* wk, u16* Wb,
              const u16* xkad, const u16* xvad, u16* AK, u16* AVt){
  int bid = blockIdx.x;
  if (bid < 8192) f2b8_body(wk, Wb, bid);
  else adresh_body(xkad, xvad, AK, AVt, bid - 8192);
}

// f2b(wv) alone
__global__ __launch_bounds__(256)
void k_f2bw(const float* w, u16* Wb){ f2b8_body(w, Wb, blockIdx.x); }

// LoRA finishers AFTER V projection. 2 elems/thread (one RoPE pair), grid (24, 4096):
// x 0..7 = q rope slabs, 8..15 = k rope slabs, 16..23 = v add slabs.
__global__ __launch_bounds__(256)
void k_finish(const u16* __restrict__ xq, const u16* __restrict__ xk, u16* __restrict__ xv,
              const float* __restrict__ tpart,
              const float* __restrict__ lq2, const float* __restrict__ lk2,
              const float* __restrict__ lv2,
              const float* __restrict__ fcos, const float* __restrict__ fsin,
              u16* __restrict__ Qb, u16* __restrict__ Kb){
  __shared__ float ts[16];
  const int m = blockIdx.y;
  const int b = m >> 10, s = m & 1023;
  const int kind = blockIdx.x >> 3;   // 0=q,1=k,2=v
  const int slab = blockIdx.x & 7;
  const int tid = threadIdx.x;
  const float* l2 = (kind == 0) ? lq2 : (kind == 1) ? lk2 : lv2;
  if (tid < 16){
    float a = 0.f;
#pragma unroll
    for (int p = 0; p < 8; p++) a += tpart[((size_t)p * 4096 + m) * 128 + kind * 16 + tid];
    ts[tid] = a;
  }
  __syncthreads();
  float tsr[16];
#pragma unroll
  for (int r = 0; r < 16; r++) tsr[r] = ts[r];

  const int o0 = slab * 512 + tid * 2;
  float ss[2];
#pragma unroll
  for (int e = 0; e < 2; e++){
    const fx4* lv = (const fx4*)(l2 + (size_t)(o0 + e) * 16);
    float acc = 0.f;
#pragma unroll
    for (int q = 0; q < 4; q++){
      fx4 lq = lv[q];
      acc += tsr[q*4]*lq[0] + tsr[q*4+1]*lq[1] + tsr[q*4+2]*lq[2] + tsr[q*4+3]*lq[3];
    }
    ss[e] = acc;
  }

  if (kind < 2){
    const u16* xin = (kind == 0) ? xq : xk;
    u16* outp = (kind == 0) ? Qb : Kb;
    unsigned cur = *(const unsigned*)&xin[(size_t)m * 4096 + o0];
    float v0 = b2f((u16)(cur & 0xFFFF)) + ss[0];
    float v1 = b2f((u16)(cur >> 16)) + ss[1];
    const int h = o0 >> 7, dd = o0 & 127;
    const int j = dd >> 1;
    float c = fcos[s * 64 + j], sn = fsin[s * 64 + j];
    float re = v0 * c - v1 * sn;
    float im = v0 * sn + v1 * c;
    size_t oi = (((size_t)(b * Hz + h)) * Sz + s) * HDz + dd;
    *(unsigned*)&outp[oi] = (unsigned)f2b(re) | ((unsigned)f2b(im) << 16);
  } else {
    u16* yp = xv + (size_t)m * 4096 + o0;
    unsigned cur = *(unsigned*)yp;
    float v0 = b2f((u16)(cur & 0xFFFF)) + ss[0];
    float v1 = b2f((u16)(cur >> 16)) + ss[1];
    *(unsigned*)yp = (unsigned)f2b(v0) | ((unsigned)f2b(v1) << 16);
  }
}

__global__ __launch_bounds__(256)
void k_combo7(const float* wo, u16* Wb, const float* lo1, u16* l1b){
  int bid = blockIdx.x;
  if (bid < 8192) f2b8_body(wo, Wb, bid);
  else lo1pad_body(lo1, l1b, bid - 8192);
}

__global__ __launch_bounds__(256)
void k_gemm_lora(const u16* A, const u16* Bm, float* Cpart, int K){
  __shared__ __align__(16) u16 sh[2][128][64];
  gemm_lora_body(&sh[0][0][0], &sh[1][0][0], A, Bm, Cpart, K, blockIdx.x);
}

// final LoRA add into f32 output: 1 elem/thread, grid (16, 4096)
__global__ __launch_bounds__(256)
void k_loraaddf(float* __restrict__ y, const float* __restrict__ tp, const float* __restrict__ l2){
  __shared__ float ts[16];
  const int m = blockIdx.y;
  const int o = blockIdx.x * 256 + threadIdx.x;
  if (threadIdx.x < 16){
    float a = 0.f;
#pragma unroll
    for (int p = 0; p < 8; p++) a += tp[((size_t)p * 4096 + m) * 128 + threadIdx.x];
    ts[threadIdx.x] = a;
  }
  __syncthreads();
  const fx4* lv = (const fx4*)(l2 + (size_t)o * 16);
  float s = 0.f;
#pragma unroll
  for (int q = 0; q < 4; q++){
    fx4 lq = lv[q];
    s += ts[q*4]*lq[0] + ts[q*4+1]*lq[1] + ts[q*4+2]*lq[2] + ts[q*4+3]*lq[3];
  }
  y[(size_t)m * 4096 + o] += s;
}

// ---------- V: (B,S,H,HD) -> Vt (B,H,HD,S) ----------
__global__ __launch_bounds__(256)
void k_vtrans(const u16* __restrict__ x, u16* __restrict__ vt){
  __shared__ __align__(16) u16 tile[64][128];
  int bid = blockIdx.x;
  int bh = bid >> 4;
  int b = bh >> 5, h = bh & 31;
  int s0 = (bid & 15) * 64;
  int tid = threadIdx.x;
#pragma unroll
  for (int i = 0; i < 4; i++){
    int c = i * 256 + tid;
    int ss = c >> 4, d8 = (c & 15) << 3;
    *(short8*)&tile[ss][d8] =
      *(const short8*)&x[(size_t)(b * Sz + s0 + ss) * DIMz + h * HDz + d8];
  }
  __syncthreads();
#pragma unroll
  for (int i = 0; i < 4; i++){
    int c = i * 256 + tid;
    int d = c >> 3, s8 = (c & 7) << 3;
    short8 v;
#pragma unroll
    for (int k = 0; k < 8; k++) v[k] = (short)tile[s8 + k][d];
    *(short8*)&vt[((size_t)bh * HDz + d) * Sz + s0 + s8] = v;
  }
}

// ---------- 256x256 8-phase counted-vmcnt NT bf16 GEMM ----------
#define PHASE(BUF, P, STAGE_STMT, VM_STMT)                                          \
  {                                                                                 \
    if ((P) == 0){                                                                  \
      _Pragma("unroll")                                                             \
      for (int nj = 0; nj < 4; nj++)                                                \
        _Pragma("unroll")                                                           \
        for (int kk = 0; kk < 2; kk++)                                              \
          bf[nj][kk] = *ldsRd(&lds[BUF][2 + (wn >> 1)][0][0], 128,                  \
                              (wn & 1) * 64 + nj * 16 + lrow, kk * 32 + lgrp * 8);  \
    }                                                                               \
    short8 af[2][2];                                                                \
    _Pragma("unroll")                                                               \
    for (int m2 = 0; m2 < 2; m2++)                                                  \
      _Pragma("unroll")                                                             \
      for (int kk = 0; kk < 2; kk++)                                                \
        af[m2][kk] = *ldsRd(&lds[BUF][wm][0][0], 128,                               \
                            ((P) * 2 + m2) * 16 + lrow, kk * 32 + lgrp * 8);        \
    STAGE_STMT;                                                                     \
    bar();                                                                          \
    __builtin_amdgcn_s_setprio(1);                                                  \
    _Pragma("unroll")                                                               \
    for (int m2 = 0; m2 < 2; m2++)                                                  \
      _Pragma("unroll")                                                             \
      for (int nj = 0; nj < 4; nj++)                                                \
        _Pragma("unroll")                                                           \
        for (int kk = 0; kk < 2; kk++)                                              \
          acc[(P) * 2 + m2][nj] = __builtin_amdgcn_mfma_f32_16x16x32_bf16(          \
              af[m2][kk], bf[nj][kk], acc[(P) * 2 + m2][nj], 0, 0, 0);              \
    __builtin_amdgcn_s_setprio(0);                                                  \
    VM_STMT;                                                                        \
    bar();                                                                          \
  }

__global__ __launch_bounds__(512, 2)
void gemm_nt256(const u16* __restrict__ A, const u16* __restrict__ Bm,
                void* __restrict__ Cp, int N, int K, int outBf16, int nbx){
  __shared__ __align__(16) u16 lds[2][4][128][64];
  const int tid = threadIdx.x;
  const int l = tid & 63, w = tid >> 6;
  const int lrow = l & 15, lgrp = l >> 4;
  const int wm = w >> 2, wn = w & 3;

  const int nwg = gridDim.x;
  const int cpx = nwg >> 3;
  const int swz = (blockIdx.x & 7) * cpx + (blockIdx.x >> 3);
  const int by = swz / nbx, bx = swz - by * nbx;
  const int bm = by << 8, bn = bx << 8;

  const u16* A0s = A  + (size_t)bm * K;
  const u16* A1s = A0s + (size_t)128 * K;
  const u16* B0s = Bm + (size_t)bn * K;
  const u16* B1s = B0s + (size_t)128 * K;
  const int nt = K >> 6;

  const fx4 fz = {0.f, 0.f, 0.f, 0.f};
  fx4 acc[8][4];
#pragma unroll
  for (int i = 0; i < 8; i++)
#pragma unroll
    for (int j = 0; j < 4; j++) acc[i][j] = fz;

  auto STAGEH = [&](int buf, int reg, const u16* src, int t){
#pragma unroll
    for (int r = 0; r < 2; r++){
      int c = r * 512 + tid;
      int row = c >> 3, cs = c & 7;
      int off = (cs ^ (row & 7)) << 3;
      gload16(src + (size_t)row * K + t * 64 + off, &lds[buf][reg][0][0] + c * 8);
    }
  };

  STAGEH(0, 0, A0s, 0); STAGEH(0, 1, A1s, 0);
  STAGEH(0, 2, B0s, 0); STAGEH(0, 3, B1s, 0);
  STAGEH(1, 2, B0s, 1); STAGEH(1, 3, B1s, 1);
  asm volatile("s_waitcnt vmcnt(4)" ::: "memory");
  bar();

  short8 bf[4][2];
  const int ni = nt >> 1;
  for (int i = 0; i < ni; i++){
    const int t0 = 2 * i, t1 = 2 * i + 1;
    const bool more = (i < ni - 1);
    PHASE(0, 0, { STAGEH(1, 0, A0s, t1); }, {});
    PHASE(0, 1, { STAGEH(1, 1, A1s, t1); }, {});
    PHASE(0, 2, { if (more) STAGEH(0, 2, B0s, t0 + 2); }, {});
    PHASE(0, 3, { if (more) STAGEH(0, 3, B1s, t0 + 2); },
          { if (more) { asm volatile("s_waitcnt vmcnt(4)" ::: "memory"); }
            else      { asm volatile("s_waitcnt vmcnt(0)" ::: "memory"); } });
    PHASE(1, 0, { if (more) STAGEH(0, 0, A0s, t0 + 2); }, {});
    PHASE(1, 1, { if (more) STAGEH(0, 1, A1s, t0 + 2); }, {});
    PHASE(1, 2, { if (more) STAGEH(1, 2, B0s, t1 + 2); }, {});
    PHASE(1, 3, { if (more) STAGEH(1, 3, B1s, t1 + 2); },
          { if (more) { asm volatile("s_waitcnt vmcnt(4)" ::: "memory"); } });
  }

  if (outBf16){
    u16* C = (u16*)Cp;
#pragma unroll
    for (int mi = 0; mi < 8; mi++)
#pragma unroll
      for (int r = 0; r < 4; r++){
        int gm = bm + wm * 128 + mi * 16 + lgrp * 4 + r;
        u16* crow = C + (size_t)gm * N + bn + wn * 64 + lrow;
#pragma unroll
        for (int nj = 0; nj < 4; nj++) crow[nj * 16] = f2b(acc[mi][nj][r]);
      }
  } else {
    float* C = (float*)Cp;
#pragma unroll
    for (int mi = 0; mi < 8; mi++)
#pragma unroll
      for (int r = 0; r < 4; r++){
        int gm = bm + wm * 128 + mi * 16 + lgrp * 4 + r;
        float* crow = C + (size_t)gm * N + bn + wn * 64 + lrow;
#pragma unroll
        for (int nj = 0; nj < 4; nj++) crow[nj * 16] = acc[mi][nj][r];
      }
  }
}

// ---------- flash attention + gated adapter attention ----------
__global__ __launch_bounds__(512)
void k_attn(const u16* __restrict__ Q, const u16* __restrict__ Kg,
            const u16* __restrict__ Vt, const u16* __restrict__ AKg,
            const u16* __restrict__ AVg, const float* __restrict__ gate,
            u16* __restrict__ outp){
  __shared__ __align__(16) u16 Ks[2][64][128];
  __shared__ __align__(16) u16 Vs[2][128][64];
  __shared__ __align__(16) u16 Ps[8][16][64];

  const int blk = blockIdx.x;
  const int jj = blk >> 3;
  const int bh = (blk & 7) * 16 + (jj & 15);
  const int bx = jj >> 4;
  const int b = bh >> 5, h = bh & 31;
  const int q0 = bx * 128;
  const int tid = threadIdx.x;
  const int w = tid >> 6, l = tid & 63;
  const int lrow = l & 15, lgrp = l >> 4;

  const u16* Qb = Q  + (size_t)bh * (Sz * HDz) + (size_t)q0 * HDz;
  const u16* Kb = Kg + (size_t)bh * (Sz * HDz);
  const u16* Vb = Vt + (size_t)bh * (HDz * Sz);
  u16* PsB = &Ps[0][0][0];

  short8 aq[4];
#pragma unroll
  for (int kk = 0; kk < 4; kk++)
    aq[kk] = *(const short8*)&Qb[(size_t)(w*16 + lrow) * HDz + kk*32 + lgrp*8];

  const fx4 fz = {0.f, 0.f, 0.f, 0.f};
  fx4 o[8];
#pragma unroll
  for (int i = 0; i < 8; i++) o[i] = fz;
  float mrow[4], lsum[4];
#pragma unroll
  for (int r = 0; r < 4; r++){ mrow[r] = -1e30f; lsum[r] = 0.f; }

  const float scale2 = 0.088388347648318447f * 1.4426950408889634f;
  const int qwbase = q0 + w * 16;
  const int qrowbase = qwbase + lgrp * 4;
  const int ktiles = 2 * bx + 2;

  auto STAGE = [&](int buf, int kt){
    const int k0 = kt * 64;
#pragma unroll
    for (int r = 0; r < 2; r++){
      int c = r * 512 + tid;
      int row = c >> 4, cs = c & 15;
      int gcs = cs ^ (row & 7);
      gload16(Kb + (size_t)(k0 + row) * HDz + gcs * 8, ((u16*)&Ks[buf][0][0]) + c * 8);
    }
#pragma unroll
    for (int r = 0; r < 2; r++){
      int c = r * 512 + tid;
      int row = c >> 3, cs = c & 7;
      int gcs = cs ^ (row & 7);
      gload16(Vb + (size_t)row * Sz + k0 + gcs * 8, ((u16*)&Vs[buf][0][0]) + c * 8);
    }
  };

  STAGE(0, 0);
  asm volatile("s_waitcnt vmcnt(0)" ::: "memory");
  bar();

  for (int kt = 0; kt < ktiles; kt++){
    const int cur = kt & 1;
    if (kt + 1 < ktiles) STAGE(cur ^ 1, kt + 1);
    const int k0 = kt * 64;

    if (k0 <= qwbase + 15){
      fx4 sc[4];
#pragma unroll
      for (int j = 0; j < 4; j++) sc[j] = fz;
      __builtin_amdgcn_s_setprio(1);
#pragma unroll
      for (int kk = 0; kk < 4; kk++){
#pragma unroll
        for (int j = 0; j < 4; j++){
          short8 bk = *ldsRd(&Ks[cur][0][0], 256, j*16 + lrow, kk*32 + lgrp*8);
          sc[j] = __builtin_amdgcn_mfma_f32_16x16x32_bf16(aq[kk], bk, sc[j], 0, 0, 0);
        }
      }
      __builtin_amdgcn_s_setprio(0);
      const bool domask = (k0 + 63 > qwbase);
      float tm[4];
#pragma unroll
      for (int r = 0; r < 4; r++){
        float mx = -1e30f;
#pragma unroll
        for (int j = 0; j < 4; j++){
          float v = sc[j][r] * scale2;
          if (domask){
            int kcol = k0 + j*16 + lrow;
            if (kcol > qrowbase + r) v = -1e30f;
          }
          sc[j][r] = v;
          mx = fmaxf(mx, v);
        }
#pragma unroll
        for (int d = 1; d < 16; d <<= 1) mx = fmaxf(mx, __shfl_xor(mx, d));
        tm[r] = mx;
      }
      if (!__all(tm[0] <= mrow[0] + 11.5f && tm[1] <= mrow[1] + 11.5f &&
                 tm[2] <= mrow[2] + 11.5f && tm[3] <= mrow[3] + 11.5f)){
        float esc[4];
#pragma unroll
        for (int r = 0; r < 4; r++){
          float nm = fmaxf(mrow[r], tm[r]);
          esc[r] = exp2f(mrow[r] - nm);
          mrow[r] = nm;
          lsum[r] *= esc[r];
        }
#pragma unroll
        for (int j = 0; j < 8; j++)
#pragma unroll
          for (int r = 0; r < 4; r++) o[j][r] *= esc[r];
      }
#pragma unroll
      for (int r = 0; r < 4; r++){
        float s = 0.f;
#pragma unroll
        for (int j = 0; j < 4; j++){
          float p = exp2f(sc[j][r] - mrow[r]);
          sc[j][r] = p;
          s += p;
        }
#pragma unroll
        for (int d = 1; d < 16; d <<= 1) s += __shfl_xor(s, d);
        lsum[r] += s;
      }
#pragma unroll
      for (int j = 0; j < 4; j++)
#pragma unroll
        for (int r = 0; r < 4; r++)
          *psPtr(PsB, w, lgrp*4 + r, j*16 + lrow) = f2b(sc[j][r]);
      __builtin_amdgcn_s_setprio(1);
#pragma unroll
      for (int kk = 0; kk < 2; kk++){
        short8 ap = *(const short8*)psPtr(PsB, w, lrow, kk*32 + lgrp*8);
#pragma unroll
        for (int j = 0; j < 8; j++){
          short8 bv = *ldsRd(&Vs[cur][0][0], 128, j*16 + lrow, kk*32 + lgrp*8);
          o[j] = __builtin_amdgcn_mfma_f32_16x16x32_bf16(ap, bv, o[j], 0, 0, 0);
        }
      }
      __builtin_amdgcn_s_setprio(0);
    }

    asm volatile("s_waitcnt vmcnt(0)" ::: "memory");
    bar();
  }

#pragma unroll
  for (int j = 0; j < 8; j++)
#pragma unroll
    for (int r = 0; r < 4; r++) o[j][r] /= lsum[r];

  fx4 s2 = fz;
  const u16* AKb = AKg + (size_t)bh * (16 * HDz);
#pragma unroll
  for (int kk = 0; kk < 4; kk++){
    short8 bk = *(const short8*)&AKb[(size_t)lrow * HDz + kk*32 + lgrp*8];
    s2 = __builtin_amdgcn_mfma_f32_16x16x32_bf16(aq[kk], bk, s2, 0, 0, 0);
  }
  const float g = tanhf(gate[h]);
#pragma unroll
  for (int r = 0; r < 4; r++){
    float v = s2[r] * scale2;
    if (lrow >= ALz) v = -1e30f;
    float mx = v;
#pragma unroll
    for (int d = 1; d < 16; d <<= 1) mx = fmaxf(mx, __shfl_xor(mx, d));
    float p = exp2f(v - mx);
    float s = p;
#pragma unroll
    for (int d = 1; d < 16; d <<= 1) s += __shfl_xor(s, d);
    float p2 = g * p / s;
    *psPtr(PsB, w, lgrp*4 + r, lrow) = f2b(p2);
    *psPtr(PsB, w, lgrp*4 + r, 16 + lrow) = 0;
  }
  {
    const u16* AVb = AVg + (size_t)bh * (HDz * 32);
    short8 ap = *(const short8*)psPtr(PsB, w, lrow, lgrp*8);
#pragma unroll
    for (int j = 0; j < 8; j++){
      short8 bv = *(const short8*)&AVb[(size_t)(j*16 + lrow) * 32 + lgrp*8];
      o[j] = __builtin_amdgcn_mfma_f32_16x16x32_bf16(ap, bv, o[j], 0, 0, 0);
    }
  }

  // vectorized output: two 64-col halves restaged through Ps[w] (per-wave, no barrier)
  u16* ob = outp + (size_t)(b * Sz + q0 + w * 16) * DIMz + h * HDz;
  const int rr = l >> 2, cc = (l & 3) * 16;
#pragma unroll
  for (int half = 0; half < 2; half++){
#pragma unroll
    for (int j = 0; j < 4; j++)
#pragma unroll
      for (int r = 0; r < 4; r++)
        Ps[w][lgrp*4 + r][j*16 + lrow] = f2b(o[half*4 + j][r]);
    short8 s0 = *(const short8*)&Ps[w][rr][cc];
    short8 s1 = *(const short8*)&Ps[w][rr][cc + 8];
    *(short8*)&ob[(size_t)rr * DIMz + half*64 + cc] = s0;
    *(short8*)&ob[(size_t)rr * DIMz + half*64 + cc + 8] = s1;
  }
}

// ---------- host ----------
extern "C" void kernel_launch(void* const* d_in, const int* in_sizes, int n_in,
                              void* d_out, int out_size, void* d_ws, size_t ws_size,
                              hipStream_t stream){
  const float* x    = (const float*)d_in[0];
  const float* adap = (const float*)d_in[1];
  const float* wq   = (const float*)d_in[2];
  const float* wk   = (const float*)d_in[3];
  const float* wv   = (const float*)d_in[4];
  const float* wo   = (const float*)d_in[5];
  const float* lq1  = (const float*)d_in[6];
  const float* lq2  = (const float*)d_in[7];
  const float* lk1  = (const float*)d_in[8];
  const float* lk2  = (const float*)d_in[9];
  const float* lv1  = (const float*)d_in[10];
  const float* lv2  = (const float*)d_in[11];
  const float* lo1  = (const float*)d_in[12];
  const float* lo2  = (const float*)d_in[13];
  const float* gate = (const float*)d_in[14];
  const float* fcos = (const float*)d_in[15];
  const float* fsin = (const float*)d_in[16];

  const size_t MB = 1024 * 1024;
  char* ws = (char*)d_ws;
  u16*  Xcat = (u16*)(ws);                 // 4352x4096 bf16 (34 MB); later Q
  u16*  Wb   = (u16*)(ws + 34 * MB);       // 32 MB; later K
  u16*  xq   = (u16*)(ws + 66 * MB);       // 34 MB; later attn_out
  u16*  xk   = (u16*)(ws + 100 * MB);      // 34 MB
  u16*  xv   = (u16*)(ws + 134 * MB);      // 34 MB
  u16*  Vt   = (u16*)(ws + 168 * MB);      // 32 MB; tpart (16 MB f32) aliases (disjoint lifetimes)
  float* tpart = (float*)(ws + 168 * MB);  // [8][4096][128] f32
  u16*  l1b  = (u16*)(ws + 200 * MB);      // 1 MB
  u16*  AKb  = (u16*)(ws + 201 * MB);      // 0.5 MB
  u16*  AVb  = (u16*)(ws + 201 * MB + 512 * 1024); // 1 MB
  u16*  Qb = Xcat;
  u16*  Kb = Wb;
  u16*  attn = xq;
  float* out = (float*)d_out;

  dim3 blk(256);
  const u16* Xad = Xcat + (size_t)4096 * 4096;
  u16* xkad = xk + (size_t)4096 * 4096;
  u16* xvad = xv + (size_t)4096 * 4096;

  // 1: xcat + l1cat
  k_combo1<<<dim3(8960), blk, 0, stream>>>(x, adap, Xcat, lq1, lk1, lv1, l1b);
  // 2: f2b(wq) + split-K LoRA GEMM + adapter K/V GEMMs (read f32 weights)
  k_combo2<<<dim3(8576), blk, 0, stream>>>(wq, Wb, Xcat, l1b, tpart, Xad, wk, wv, xkad, xvad);
  // 3: Q projection
  gemm_nt256<<<dim3(256), dim3(512), 0, stream>>>(Xcat, Wb, xq, 4096, 4096, 1, 16);
  // 4: f2b(wk) + adapter reshape
  k_combo3<<<dim3(8320), blk, 0, stream>>>(wk, Wb, xkad, xvad, AKb, AVb);
  // 5: K projection
  gemm_nt256<<<dim3(256), dim3(512), 0, stream>>>(Xcat, Wb, xk, 4096, 4096, 1, 16);
  // 6: f2b(wv)
  k_f2bw<<<dim3(8192), blk, 0, stream>>>(wv, Wb);
  // 7: V projection (last reader of Xcat and of Wb=wv)
  gemm_nt256<<<dim3(256), dim3(512), 0, stream>>>(Xcat, Wb, xv, 4096, 4096, 1, 16);
  // 8: LoRA finishers: rope-q (xq->Qb=Xcat), rope-k (xk->Kb=Wb), add-v (in place)
  k_finish<<<dim3(24, 4096), blk, 0, stream>>>(xq, xk, xv, tpart, lq2, lk2, lv2,
                                               fcos, fsin, Qb, Kb);
  // 9: V transpose (tpart consumed; Vt may overwrite it)
  k_vtrans<<<dim3(2048), blk, 0, stream>>>(xv, Vt);
  // 10: attention
  k_attn<<<dim3(1024), dim3(512), 0, stream>>>(Qb, Kb, Vt, AKb, AVb, gate, attn);
  // 11: f2b(wo) + lo1 pad
  k_combo7<<<dim3(8448), blk, 0, stream>>>(wo, Wb, lo1, l1b);
  // 12: output projection
  gemm_nt256<<<dim3(256), dim3(512), 0, stream>>>(attn, Wb, out, 4096, 4096, 0, 16);
  // 13: split-K LoRA GEMM on attn output
  k_gemm_lora<<<dim3(256), blk, 0, stream>>>(attn, l1b, tpart, 4096);
  // 14: final LoRA add into f32 output
  k_loraaddf<<<dim3(16, 4096), blk, 0, stream>>>(out, tpart, lo2);
}

// Round 14
// 953.519 us; speedup vs baseline: 1.5492x; 1.3387x over previous
//
#include <hip/hip_runtime.h>
#include <stdint.h>

#define Bz 4
#define Sz 1024
#define DIMz 4096
#define Hz 32
#define HDz 128
#define ALz 10

typedef unsigned short u16;
typedef __attribute__((ext_vector_type(8))) short short8;
typedef __attribute__((ext_vector_type(4))) float fx4;

__device__ __forceinline__ u16 f2b(float f){
  union { float f; unsigned u; } v; v.f = f;
  unsigned r = v.u + 0x7FFFu + ((v.u >> 16) & 1u);
  return (u16)(r >> 16);
}
__device__ __forceinline__ float b2f(u16 h){
  union { unsigned u; float f; } v; v.u = ((unsigned)h) << 16; return v.f;
}
__device__ __forceinline__ short8 pack8(fx4 a, fx4 b){
  short8 v;
  v[0]=(short)f2b(a[0]); v[1]=(short)f2b(a[1]); v[2]=(short)f2b(a[2]); v[3]=(short)f2b(a[3]);
  v[4]=(short)f2b(b[0]); v[5]=(short)f2b(b[1]); v[6]=(short)f2b(b[2]); v[7]=(short)f2b(b[3]);
  return v;
}
__device__ __forceinline__ void gload16(const void* g, void* l){
  __builtin_amdgcn_global_load_lds(
    (const __attribute__((address_space(1))) uint32_t*)g,
    (__attribute__((address_space(3))) uint32_t*)l, 16, 0, 0);
}
__device__ __forceinline__ void bar(){
  asm volatile("" ::: "memory");
  __builtin_amdgcn_s_barrier();
  asm volatile("" ::: "memory");
}

// ---------- LDS swizzle helper (T2: byte ^= (row&7)<<4) ----------
__device__ __forceinline__ const short8* ldsRd(const u16* base, int rowBytes, int row, int colElem){
  unsigned byte = (unsigned)(row * rowBytes + colElem * 2);
  byte ^= (unsigned)((row & 7) << 4);
  return (const short8*)((const char*)base + byte);
}
__device__ __forceinline__ u16* psPtr(u16* base, int w, int row, int colElem){
  unsigned byte = (unsigned)(row * 128 + colElem * 2);
  byte ^= (unsigned)((row & 7) << 4);
  return (u16*)((char*)base + w * 2048 + byte);
}

// ================= aux bodies =================
__device__ __forceinline__ void f2b8_body(const float* __restrict__ src, u16* __restrict__ dst, int bid){
  size_t i = ((size_t)bid * 256 + threadIdx.x) * 8;
  *(short8*)(dst + i) = pack8(*(const fx4*)(src + i), *(const fx4*)(src + i + 4));
}

__device__ __forceinline__ void xcat_body(const float* __restrict__ x, const float* __restrict__ ad,
                                          u16* __restrict__ dst, int bid){
  size_t i = ((size_t)bid * 256 + threadIdx.x) * 8;
  int row = (int)(i >> 12), col = (int)(i & 4095);
  short8 v = {0,0,0,0,0,0,0,0};
  const float* s = nullptr;
  if (row < 4096) s = x + i;
  else if (row < 4096 + Bz*ALz) s = ad + (size_t)(row - 4096) * 4096 + col;
  if (s) v = pack8(*(const fx4*)s, *(const fx4*)(s + 4));
  *(short8*)(dst + i) = v;
}

__device__ __forceinline__ void l1cat_body(const float* __restrict__ a, const float* __restrict__ b,
                                           const float* __restrict__ c, u16* __restrict__ dst, int bid){
  size_t i = ((size_t)bid * 256 + threadIdx.x) * 8;
  int row = (int)(i >> 12), col = (int)(i & 4095);
  short8 v = {0,0,0,0,0,0,0,0};
  const float* s = nullptr;
  if (row < 16) s = a + i;
  else if (row < 32) s = b + (size_t)(row - 16) * 4096 + col;
  else if (row < 48) s = c + (size_t)(row - 32) * 4096 + col;
  if (s) v = pack8(*(const fx4*)s, *(const fx4*)(s + 4));
  *(short8*)(dst + i) = v;
}

__device__ __forceinline__ void lo1pad_body(const float* __restrict__ src, u16* __restrict__ dst, int bid){
  size_t i = ((size_t)bid * 256 + threadIdx.x) * 8;
  int row = (int)(i >> 12);
  short8 v = {0,0,0,0,0,0,0,0};
  if (row < 16) v = pack8(*(const fx4*)(src + i), *(const fx4*)(src + i + 4));
  *(short8*)(dst + i) = v;
}

// split-K LoRA-l1 GEMM body (128^2 tile, K-slice 512) — writes f32 partials
__device__ __forceinline__ void gemm_lora_body(u16* shA, u16* shB,
    const u16* __restrict__ A, const u16* __restrict__ Bm, float* __restrict__ Cpart,
    int K, int bid2){
  const int tid = threadIdx.x;
  const int w = tid >> 6, l = tid & 63;
  const int lrow = l & 15, lgrp = l >> 4;
  const int ks = bid2 & 7;
  const int bm = (bid2 >> 3) * 128;
  const int wr = (w >> 1) * 64, wc = (w & 1) * 64;

  const fx4 fz = {0.f, 0.f, 0.f, 0.f};
  fx4 acc[4][4];
#pragma unroll
  for (int i = 0; i < 4; i++)
#pragma unroll
    for (int j = 0; j < 4; j++) acc[i][j] = fz;

  const u16* Abase = A + (size_t)bm * K;
  const int kbeg = ks * 512, kend = kbeg + 512;

  for (int k0 = kbeg; k0 < kend; k0 += 64){
    __syncthreads();
#pragma unroll
    for (int i = 0; i < 4; i++){
      int c = i * 256 + tid;
      int row = c >> 3, cs = c & 7;
      int off = (cs ^ (row & 7)) << 3;
      gload16(Abase + (size_t)row * K + k0 + off, shA + c * 8);
      gload16(Bm + (size_t)row * K + k0 + off, shB + c * 8);
    }
    __syncthreads();
#pragma unroll
    for (int kk = 0; kk < 2; kk++){
      short8 a[4], b[4];
#pragma unroll
      for (int i = 0; i < 4; i++) a[i] = *ldsRd(shA, 128, wr + i*16 + lrow, kk*32 + lgrp*8);
#pragma unroll
      for (int j = 0; j < 4; j++) b[j] = *ldsRd(shB, 128, wc + j*16 + lrow, kk*32 + lgrp*8);
#pragma unroll
      for (int i = 0; i < 4; i++)
#pragma unroll
        for (int j = 0; j < 4; j++)
          acc[i][j] = __builtin_amdgcn_mfma_f32_16x16x32_bf16(a[i], b[j], acc[i][j], 0, 0, 0);
    }
  }

  float* C = Cpart + (size_t)ks * 4096 * 128;
#pragma unroll
  for (int i = 0; i < 4; i++)
#pragma unroll
    for (int r = 0; r < 4; r++){
      int gm = bm + wr + i*16 + lgrp*4 + r;
      float* crow = C + (size_t)gm * 128 + wc + lrow;
#pragma unroll
      for (int j = 0; j < 4; j++) crow[j*16] = acc[i][j][r];
    }
}

// thin adapter GEMM body reading f32 weights (Wb-independent)
__device__ __forceinline__ void adgemm_f32_body(const u16* __restrict__ A, const float* __restrict__ Bw,
    u16* __restrict__ C, int N, int K, int bid){
  const int tid = threadIdx.x;
  const int w = tid >> 6, l = tid & 63;
  const int lrow = l & 15, lgrp = l >> 4;
  const int n0 = bid * 64 + w * 16;

  const fx4 fz = {0.f, 0.f, 0.f, 0.f};
  fx4 acc[3];
#pragma unroll
  for (int i = 0; i < 3; i++) acc[i] = fz;

  const float* Brow = Bw + (size_t)(n0 + lrow) * K + lgrp * 8;
  const u16* Arow = A + (size_t)lrow * K + lgrp * 8;
  for (int k0 = 0; k0 < K; k0 += 32){
    fx4 b0 = *(const fx4*)(Brow + k0);
    fx4 b1 = *(const fx4*)(Brow + k0 + 4);
    short8 b = pack8(b0, b1);
#pragma unroll
    for (int mf = 0; mf < 3; mf++){
      short8 a = *(const short8*)(Arow + (size_t)mf * 16 * K + k0);
      acc[mf] = __builtin_amdgcn_mfma_f32_16x16x32_bf16(a, b, acc[mf], 0, 0, 0);
    }
  }
#pragma unroll
  for (int mf = 0; mf < 3; mf++)
#pragma unroll
    for (int r = 0; r < 4; r++)
      C[(size_t)(mf * 16 + lgrp * 4 + r) * N + n0 + lrow] = f2b(acc[mf][r]);
}

__device__ __forceinline__ void adresh_body(const u16* __restrict__ akf, const u16* __restrict__ avf,
    u16* __restrict__ AK, u16* __restrict__ AVt, int bh){
  const int b = bh >> 5, h = bh & 31;
  const int tid = threadIdx.x;
#pragma unroll
  for (int i = 0; i < 8; i++){
    int e = i * 256 + tid;
    int jj = e >> 7, d = e & 127;
    u16 v = (jj < ALz) ? akf[(size_t)(b * ALz + jj) * DIMz + h * HDz + d] : (u16)0;
    AK[((size_t)bh * 16 + jj) * HDz + d] = v;
  }
#pragma unroll
  for (int i = 0; i < 16; i++){
    int e = i * 256 + tid;
    int d = e >> 5, jj = e & 31;
    u16 v = (jj < ALz) ? avf[(size_t)(b * ALz + jj) * DIMz + h * HDz + d] : (u16)0;
    AVt[((size_t)bh * HDz + d) * 32 + jj] = v;
  }
}

// ================= combo kernels =================
__global__ __launch_bounds__(256)
void k_combo1(const float* x, const float* ad, u16* Xcat,
              const float* lq1, const float* lk1, const float* lv1, u16* l1b){
  int bid = blockIdx.x;
  if (bid < 8704) xcat_body(x, ad, Xcat, bid);
  else l1cat_body(lq1, lk1, lv1, l1b, bid - 8704);
}

__global__ __launch_bounds__(256)
void k_combo2(const float* wq, u16* Wb,
              const u16* Xcat, const u16* l1b, float* tpart,
              const u16* Xad, const float* wk, const float* wv, u16* xkad, u16* xvad){
  __shared__ __align__(16) u16 sh[2][128][64];
  int bid = blockIdx.x;
  if (bid < 8192) f2b8_body(wq, Wb, bid);
  else if (bid < 8448) gemm_lora_body(&sh[0][0][0], &sh[1][0][0], Xcat, l1b, tpart, 4096, bid - 8192);
  else if (bid < 8512) adgemm_f32_body(Xad, wk, xkad, 4096, 4096, bid - 8448);
  else adgemm_f32_body(Xad, wv, xvad, 4096, 4096, bid - 8512);
}

// f2b(wk) + adapter reshape (xkad/xvad ready since combo2)
__global__ __launch_bounds__(256)
void k_combo3(const float* wk, u16* Wb,
              const u16* xkad, const u16* xvad, u16* AK, u16* AVt){
  int bid = blockIdx.x;
  if (bid < 8192) f2b8_body(wk, Wb, bid);
  else adresh_body(xkad, xvad, AK, AVt, bid - 8192);
}

// f2b(wv) alone
__global__ __launch_bounds__(256)
void k_f2bw(const float* w, u16* Wb){ f2b8_body(w, Wb, blockIdx.x); }

// LoRA finishers AFTER V projection. Grid (24, 128): x = kind*8+slab, y = 32-row m-block.
// Per thread: 2 o-columns, l2 rows cached in regs (gather amortized 32x over m-loop).
__global__ __launch_bounds__(256)
void k_finish(const u16* __restrict__ xq, const u16* __restrict__ xk, u16* __restrict__ xv,
              const float* __restrict__ tpart,
              const float* __restrict__ lq2, const float* __restrict__ lk2,
              const float* __restrict__ lv2,
              const float* __restrict__ fcos, const float* __restrict__ fsin,
              u16* __restrict__ Qb, u16* __restrict__ Kb){
  __shared__ float ts[32][16];
  const int kind = blockIdx.x >> 3;   // 0=q,1=k,2=v
  const int slab = blockIdx.x & 7;
  const int m0 = blockIdx.y * 32;
  const int tid = threadIdx.x;
  const float* l2 = (kind == 0) ? lq2 : (kind == 1) ? lk2 : lv2;

  // tsum for the 32 rows: 512 sums, 2 per thread (16-lane groups read 64B lines)
#pragma unroll
  for (int rep = 0; rep < 2; rep++){
    int id2 = rep * 256 + tid;         // 0..511
    int mi = id2 >> 4, c = id2 & 15;
    float a = 0.f;
#pragma unroll
    for (int p = 0; p < 8; p++)
      a += tpart[((size_t)p * 4096 + m0 + mi) * 128 + kind * 16 + c];
    ts[mi][c] = a;
  }
  __syncthreads();

  const int o0 = slab * 512 + tid * 2;
  // cache both l2 rows in registers (one-time gather, amortized over 32 m)
  fx4 l2r0[4], l2r1[4];
#pragma unroll
  for (int q = 0; q < 4; q++){
    l2r0[q] = *(const fx4*)(l2 + (size_t)o0 * 16 + q * 4);
    l2r1[q] = *(const fx4*)(l2 + (size_t)(o0 + 1) * 16 + q * 4);
  }

  const int h = o0 >> 7, dd = o0 & 127, j = dd >> 1;

  for (int mi = 0; mi < 32; mi++){
    const int m = m0 + mi;
    float ss0 = 0.f, ss1 = 0.f;
#pragma unroll
    for (int q = 0; q < 4; q++){
      fx4 tq = *(const fx4*)&ts[mi][q * 4];   // LDS broadcast (uniform addr)
      ss0 += tq[0]*l2r0[q][0] + tq[1]*l2r0[q][1] + tq[2]*l2r0[q][2] + tq[3]*l2r0[q][3];
      ss1 += tq[0]*l2r1[q][0] + tq[1]*l2r1[q][1] + tq[2]*l2r1[q][2] + tq[3]*l2r1[q][3];
    }
    if (kind < 2){
      const u16* xin = (kind == 0) ? xq : xk;
      u16* outp = (kind == 0) ? Qb : Kb;
      unsigned cur = *(const unsigned*)&xin[(size_t)m * 4096 + o0];
      float v0 = b2f((u16)(cur & 0xFFFF)) + ss0;
      float v1 = b2f((u16)(cur >> 16)) + ss1;
      const int b = m >> 10, s = m & 1023;
      float c = fcos[s * 64 + j], sn = fsin[s * 64 + j];
      float re = v0 * c - v1 * sn;
      float im = v0 * sn + v1 * c;
      size_t oi = (((size_t)(b * Hz + h)) * Sz + s) * HDz + dd;
      *(unsigned*)&outp[oi] = (unsigned)f2b(re) | ((unsigned)f2b(im) << 16);
    } else {
      u16* yp = xv + (size_t)m * 4096 + o0;
      unsigned cur = *(unsigned*)yp;
      float v0 = b2f((u16)(cur & 0xFFFF)) + ss0;
      float v1 = b2f((u16)(cur >> 16)) + ss1;
      *(unsigned*)yp = (unsigned)f2b(v0) | ((unsigned)f2b(v1) << 16);
    }
  }
}

__global__ __launch_bounds__(256)
void k_combo7(const float* wo, u16* Wb, const float* lo1, u16* l1b){
  int bid = blockIdx.x;
  if (bid < 8192) f2b8_body(wo, Wb, bid);
  else lo1pad_body(lo1, l1b, bid - 8192);
}

__global__ __launch_bounds__(256)
void k_gemm_lora(const u16* A, const u16* Bm, float* Cpart, int K){
  __shared__ __align__(16) u16 sh[2][128][64];
  gemm_lora_body(&sh[0][0][0], &sh[1][0][0], A, Bm, Cpart, K, blockIdx.x);
}

// final LoRA add into f32 output. Grid (8, 128): slab x m-block, l2 rows in regs.
__global__ __launch_bounds__(256)
void k_loraaddf(float* __restrict__ y, const float* __restrict__ tp, const float* __restrict__ l2){
  __shared__ float ts[32][16];
  const int slab = blockIdx.x;
  const int m0 = blockIdx.y * 32;
  const int tid = threadIdx.x;
#pragma unroll
  for (int rep = 0; rep < 2; rep++){
    int id2 = rep * 256 + tid;
    int mi = id2 >> 4, c = id2 & 15;
    float a = 0.f;
#pragma unroll
    for (int p = 0; p < 8; p++)
      a += tp[((size_t)p * 4096 + m0 + mi) * 128 + c];
    ts[mi][c] = a;
  }
  __syncthreads();

  const int o0 = slab * 512 + tid * 2;
  fx4 l2r0[4], l2r1[4];
#pragma unroll
  for (int q = 0; q < 4; q++){
    l2r0[q] = *(const fx4*)(l2 + (size_t)o0 * 16 + q * 4);
    l2r1[q] = *(const fx4*)(l2 + (size_t)(o0 + 1) * 16 + q * 4);
  }

  for (int mi = 0; mi < 32; mi++){
    float ss0 = 0.f, ss1 = 0.f;
#pragma unroll
    for (int q = 0; q < 4; q++){
      fx4 tq = *(const fx4*)&ts[mi][q * 4];
      ss0 += tq[0]*l2r0[q][0] + tq[1]*l2r0[q][1] + tq[2]*l2r0[q][2] + tq[3]*l2r0[q][3];
      ss1 += tq[0]*l2r1[q][0] + tq[1]*l2r1[q][1] + tq[2]*l2r1[q][2] + tq[3]*l2r1[q][3];
    }
    float* yp = y + (size_t)(m0 + mi) * 4096 + o0;
    yp[0] += ss0;
    yp[1] += ss1;
  }
}

// ---------- V: (B,S,H,HD) -> Vt (B,H,HD,S) ----------
__global__ __launch_bounds__(256)
void k_vtrans(const u16* __restrict__ x, u16* __restrict__ vt){
  __shared__ __align__(16) u16 tile[64][128];
  int bid = blockIdx.x;
  int bh = bid >> 4;
  int b = bh >> 5, h = bh & 31;
  int s0 = (bid & 15) * 64;
  int tid = threadIdx.x;
#pragma unroll
  for (int i = 0; i < 4; i++){
    int c = i * 256 + tid;
    int ss = c >> 4, d8 = (c & 15) << 3;
    *(short8*)&tile[ss][d8] =
      *(const short8*)&x[(size_t)(b * Sz + s0 + ss) * DIMz + h * HDz + d8];
  }
  __syncthreads();
#pragma unroll
  for (int i = 0; i < 4; i++){
    int c = i * 256 + tid;
    int d = c >> 3, s8 = (c & 7) << 3;
    short8 v;
#pragma unroll
    for (int k = 0; k < 8; k++) v[k] = (short)tile[s8 + k][d];
    *(short8*)&vt[((size_t)bh * HDz + d) * Sz + s0 + s8] = v;
  }
}

// ---------- 256x256 8-phase counted-vmcnt NT bf16 GEMM ----------
#define PHASE(BUF, P, STAGE_STMT, VM_STMT)                                          \
  {                                                                                 \
    if ((P) == 0){                                                                  \
      _Pragma("unroll")                                                             \
      for (int nj = 0; nj < 4; nj++)                                                \
        _Pragma("unroll")                                                           \
        for (int kk = 0; kk < 2; kk++)                                              \
          bf[nj][kk] = *ldsRd(&lds[BUF][2 + (wn >> 1)][0][0], 128,                  \
                              (wn & 1) * 64 + nj * 16 + lrow, kk * 32 + lgrp * 8);  \
    }                                                                               \
    short8 af[2][2];                                                                \
    _Pragma("unroll")                                                               \
    for (int m2 = 0; m2 < 2; m2++)                                                  \
      _Pragma("unroll")                                                             \
      for (int kk = 0; kk < 2; kk++)                                                \
        af[m2][kk] = *ldsRd(&lds[BUF][wm][0][0], 128,                               \
                            ((P) * 2 + m2) * 16 + lrow, kk * 32 + lgrp * 8);        \
    STAGE_STMT;                                                                     \
    bar();                                                                          \
    __builtin_amdgcn_s_setprio(1);                                                  \
    _Pragma("unroll")                                                               \
    for (int m2 = 0; m2 < 2; m2++)                                                  \
      _Pragma("unroll")                                                             \
      for (int nj = 0; nj < 4; nj++)                                                \
        _Pragma("unroll")                                                           \
        for (int kk = 0; kk < 2; kk++)                                              \
          acc[(P) * 2 + m2][nj] = __builtin_amdgcn_mfma_f32_16x16x32_bf16(          \
              af[m2][kk], bf[nj][kk], acc[(P) * 2 + m2][nj], 0, 0, 0);              \
    __builtin_amdgcn_s_setprio(0);                                                  \
    VM_STMT;                                                                        \
    bar();                                                                          \
  }

__global__ __launch_bounds__(512, 2)
void gemm_nt256(const u16* __restrict__ A, const u16* __restrict__ Bm,
                void* __restrict__ Cp, int N, int K, int outBf16, int nbx){
  __shared__ __align__(16) u16 lds[2][4][128][64];
  const int tid = threadIdx.x;
  const int l = tid & 63, w = tid >> 6;
  const int lrow = l & 15, lgrp = l >> 4;
  const int wm = w >> 2, wn = w & 3;

  const int nwg = gridDim.x;
  const int cpx = nwg >> 3;
  const int swz = (blockIdx.x & 7) * cpx + (blockIdx.x >> 3);
  const int by = swz / nbx, bx = swz - by * nbx;
  const int bm = by << 8, bn = bx << 8;

  const u16* A0s = A  + (size_t)bm * K;
  const u16* A1s = A0s + (size_t)128 * K;
  const u16* B0s = Bm + (size_t)bn * K;
  const u16* B1s = B0s + (size_t)128 * K;
  const int nt = K >> 6;

  const fx4 fz = {0.f, 0.f, 0.f, 0.f};
  fx4 acc[8][4];
#pragma unroll
  for (int i = 0; i < 8; i++)
#pragma unroll
    for (int j = 0; j < 4; j++) acc[i][j] = fz;

  auto STAGEH = [&](int buf, int reg, const u16* src, int t){
#pragma unroll
    for (int r = 0; r < 2; r++){
      int c = r * 512 + tid;
      int row = c >> 3, cs = c & 7;
      int off = (cs ^ (row & 7)) << 3;
      gload16(src + (size_t)row * K + t * 64 + off, &lds[buf][reg][0][0] + c * 8);
    }
  };

  STAGEH(0, 0, A0s, 0); STAGEH(0, 1, A1s, 0);
  STAGEH(0, 2, B0s, 0); STAGEH(0, 3, B1s, 0);
  STAGEH(1, 2, B0s, 1); STAGEH(1, 3, B1s, 1);
  asm volatile("s_waitcnt vmcnt(4)" ::: "memory");
  bar();

  short8 bf[4][2];
  const int ni = nt >> 1;
  for (int i = 0; i < ni; i++){
    const int t0 = 2 * i, t1 = 2 * i + 1;
    const bool more = (i < ni - 1);
    PHASE(0, 0, { STAGEH(1, 0, A0s, t1); }, {});
    PHASE(0, 1, { STAGEH(1, 1, A1s, t1); }, {});
    PHASE(0, 2, { if (more) STAGEH(0, 2, B0s, t0 + 2); }, {});
    PHASE(0, 3, { if (more) STAGEH(0, 3, B1s, t0 + 2); },
          { if (more) { asm volatile("s_waitcnt vmcnt(4)" ::: "memory"); }
            else      { asm volatile("s_waitcnt vmcnt(0)" ::: "memory"); } });
    PHASE(1, 0, { if (more) STAGEH(0, 0, A0s, t0 + 2); }, {});
    PHASE(1, 1, { if (more) STAGEH(0, 1, A1s, t0 + 2); }, {});
    PHASE(1, 2, { if (more) STAGEH(1, 2, B0s, t1 + 2); }, {});
    PHASE(1, 3, { if (more) STAGEH(1, 3, B1s, t1 + 2); },
          { if (more) { asm volatile("s_waitcnt vmcnt(4)" ::: "memory"); } });
  }

  if (outBf16){
    u16* C = (u16*)Cp;
#pragma unroll
    for (int mi = 0; mi < 8; mi++)
#pragma unroll
      for (int r = 0; r < 4; r++){
        int gm = bm + wm * 128 + mi * 16 + lgrp * 4 + r;
        u16* crow = C + (size_t)gm * N + bn + wn * 64 + lrow;
#pragma unroll
        for (int nj = 0; nj < 4; nj++) crow[nj * 16] = f2b(acc[mi][nj][r]);
      }
  } else {
    float* C = (float*)Cp;
#pragma unroll
    for (int mi = 0; mi < 8; mi++)
#pragma unroll
      for (int r = 0; r < 4; r++){
        int gm = bm + wm * 128 + mi * 16 + lgrp * 4 + r;
        float* crow = C + (size_t)gm * N + bn + wn * 64 + lrow;
#pragma unroll
        for (int nj = 0; nj < 4; nj++) crow[nj * 16] = acc[mi][nj][r];
      }
  }
}

// ---------- flash attention + gated adapter attention ----------
__global__ __launch_bounds__(512)
void k_attn(const u16* __restrict__ Q, const u16* __restrict__ Kg,
            const u16* __restrict__ Vt, const u16* __restrict__ AKg,
            const u16* __restrict__ AVg, const float* __restrict__ gate,
            u16* __restrict__ outp){
  __shared__ __align__(16) u16 Ks[2][64][128];
  __shared__ __align__(16) u16 Vs[2][128][64];
  __shared__ __align__(16) u16 Ps[8][16][64];

  const int blk = blockIdx.x;
  const int jj = blk >> 3;
  const int bh = (blk & 7) * 16 + (jj & 15);
  const int bx = jj >> 4;
  const int b = bh >> 5, h = bh & 31;
  const int q0 = bx * 128;
  const int tid = threadIdx.x;
  const int w = tid >> 6, l = tid & 63;
  const int lrow = l & 15, lgrp = l >> 4;

  const u16* Qb = Q  + (size_t)bh * (Sz * HDz) + (size_t)q0 * HDz;
  const u16* Kb = Kg + (size_t)bh * (Sz * HDz);
  const u16* Vb = Vt + (size_t)bh * (HDz * Sz);
  u16* PsB = &Ps[0][0][0];

  short8 aq[4];
#pragma unroll
  for (int kk = 0; kk < 4; kk++)
    aq[kk] = *(const short8*)&Qb[(size_t)(w*16 + lrow) * HDz + kk*32 + lgrp*8];

  const fx4 fz = {0.f, 0.f, 0.f, 0.f};
  fx4 o[8];
#pragma unroll
  for (int i = 0; i < 8; i++) o[i] = fz;
  float mrow[4], lsum[4];
#pragma unroll
  for (int r = 0; r < 4; r++){ mrow[r] = -1e30f; lsum[r] = 0.f; }

  const float scale2 = 0.088388347648318447f * 1.4426950408889634f;
  const int qwbase = q0 + w * 16;
  const int qrowbase = qwbase + lgrp * 4;
  const int ktiles = 2 * bx + 2;

  auto STAGE = [&](int buf, int kt){
    const int k0 = kt * 64;
#pragma unroll
    for (int r = 0; r < 2; r++){
      int c = r * 512 + tid;
      int row = c >> 4, cs = c & 15;
      int gcs = cs ^ (row & 7);
      gload16(Kb + (size_t)(k0 + row) * HDz + gcs * 8, ((u16*)&Ks[buf][0][0]) + c * 8);
    }
#pragma unroll
    for (int r = 0; r < 2; r++){
      int c = r * 512 + tid;
      int row = c >> 3, cs = c & 7;
      int gcs = cs ^ (row & 7);
      gload16(Vb + (size_t)row * Sz + k0 + gcs * 8, ((u16*)&Vs[buf][0][0]) + c * 8);
    }
  };

  STAGE(0, 0);
  asm volatile("s_waitcnt vmcnt(0)" ::: "memory");
  bar();

  for (int kt = 0; kt < ktiles; kt++){
    const int cur = kt & 1;
    if (kt + 1 < ktiles) STAGE(cur ^ 1, kt + 1);
    const int k0 = kt * 64;

    if (k0 <= qwbase + 15){
      fx4 sc[4];
#pragma unroll
      for (int j = 0; j < 4; j++) sc[j] = fz;
      __builtin_amdgcn_s_setprio(1);
#pragma unroll
      for (int kk = 0; kk < 4; kk++){
#pragma unroll
        for (int j = 0; j < 4; j++){
          short8 bk = *ldsRd(&Ks[cur][0][0], 256, j*16 + lrow, kk*32 + lgrp*8);
          sc[j] = __builtin_amdgcn_mfma_f32_16x16x32_bf16(aq[kk], bk, sc[j], 0, 0, 0);
        }
      }
      __builtin_amdgcn_s_setprio(0);
      const bool domask = (k0 + 63 > qwbase);
      float tm[4];
#pragma unroll
      for (int r = 0; r < 4; r++){
        float mx = -1e30f;
#pragma unroll
        for (int j = 0; j < 4; j++){
          float v = sc[j][r] * scale2;
          if (domask){
            int kcol = k0 + j*16 + lrow;
            if (kcol > qrowbase + r) v = -1e30f;
          }
          sc[j][r] = v;
          mx = fmaxf(mx, v);
        }
#pragma unroll
        for (int d = 1; d < 16; d <<= 1) mx = fmaxf(mx, __shfl_xor(mx, d));
        tm[r] = mx;
      }
      if (!__all(tm[0] <= mrow[0] + 11.5f && tm[1] <= mrow[1] + 11.5f &&
                 tm[2] <= mrow[2] + 11.5f && tm[3] <= mrow[3] + 11.5f)){
        float esc[4];
#pragma unroll
        for (int r = 0; r < 4; r++){
          float nm = fmaxf(mrow[r], tm[r]);
          esc[r] = exp2f(mrow[r] - nm);
          mrow[r] = nm;
          lsum[r] *= esc[r];
        }
#pragma unroll
        for (int j = 0; j < 8; j++)
#pragma unroll
          for (int r = 0; r < 4; r++) o[j][r] *= esc[r];
      }
#pragma unroll
      for (int r = 0; r < 4; r++){
        float s = 0.f;
#pragma unroll
        for (int j = 0; j < 4; j++){
          float p = exp2f(sc[j][r] - mrow[r]);
          sc[j][r] = p;
          s += p;
        }
#pragma unroll
        for (int d = 1; d < 16; d <<= 1) s += __shfl_xor(s, d);
        lsum[r] += s;
      }
#pragma unroll
      for (int j = 0; j < 4; j++)
#pragma unroll
        for (int r = 0; r < 4; r++)
          *psPtr(PsB, w, lgrp*4 + r, j*16 + lrow) = f2b(sc[j][r]);
      __builtin_amdgcn_s_setprio(1);
#pragma unroll
      for (int kk = 0; kk < 2; kk++){
        short8 ap = *(const short8*)psPtr(PsB, w, lrow, kk*32 + lgrp*8);
#pragma unroll
        for (int j = 0; j < 8; j++){
          short8 bv = *ldsRd(&Vs[cur][0][0], 128, j*16 + lrow, kk*32 + lgrp*8);
          o[j] = __builtin_amdgcn_mfma_f32_16x16x32_bf16(ap, bv, o[j], 0, 0, 0);
        }
      }
      __builtin_amdgcn_s_setprio(0);
    }

    asm volatile("s_waitcnt vmcnt(0)" ::: "memory");
    bar();
  }

#pragma unroll
  for (int j = 0; j < 8; j++)
#pragma unroll
    for (int r = 0; r < 4; r++) o[j][r] /= lsum[r];

  fx4 s2 = fz;
  const u16* AKb = AKg + (size_t)bh * (16 * HDz);
#pragma unroll
  for (int kk = 0; kk < 4; kk++){
    short8 bk = *(const short8*)&AKb[(size_t)lrow * HDz + kk*32 + lgrp*8];
    s2 = __builtin_amdgcn_mfma_f32_16x16x32_bf16(aq[kk], bk, s2, 0, 0, 0);
  }
  const float g = tanhf(gate[h]);
#pragma unroll
  for (int r = 0; r < 4; r++){
    float v = s2[r] * scale2;
    if (lrow >= ALz) v = -1e30f;
    float mx = v;
#pragma unroll
    for (int d = 1; d < 16; d <<= 1) mx = fmaxf(mx, __shfl_xor(mx, d));
    float p = exp2f(v - mx);
    float s = p;
#pragma unroll
    for (int d = 1; d < 16; d <<= 1) s += __shfl_xor(s, d);
    float p2 = g * p / s;
    *psPtr(PsB, w, lgrp*4 + r, lrow) = f2b(p2);
    *psPtr(PsB, w, lgrp*4 + r, 16 + lrow) = 0;
  }
  {
    const u16* AVb = AVg + (size_t)bh * (HDz * 32);
    short8 ap = *(const short8*)psPtr(PsB, w, lrow, lgrp*8);
#pragma unroll
    for (int j = 0; j < 8; j++){
      short8 bv = *(const short8*)&AVb[(size_t)(j*16 + lrow) * 32 + lgrp*8];
      o[j] = __builtin_amdgcn_mfma_f32_16x16x32_bf16(ap, bv, o[j], 0, 0, 0);
    }
  }

  // vectorized output: two 64-col halves restaged through Ps[w] (per-wave, no barrier)
  u16* ob = outp + (size_t)(b * Sz + q0 + w * 16) * DIMz + h * HDz;
  const int rr = l >> 2, cc = (l & 3) * 16;
#pragma unroll
  for (int half = 0; half < 2; half++){
#pragma unroll
    for (int j = 0; j < 4; j++)
#pragma unroll
      for (int r = 0; r < 4; r++)
        Ps[w][lgrp*4 + r][j*16 + lrow] = f2b(o[half*4 + j][r]);
    short8 s0 = *(const short8*)&Ps[w][rr][cc];
    short8 s1 = *(const short8*)&Ps[w][rr][cc + 8];
    *(short8*)&ob[(size_t)rr * DIMz + half*64 + cc] = s0;
    *(short8*)&ob[(size_t)rr * DIMz + half*64 + cc + 8] = s1;
  }
}

// ---------- host ----------
extern "C" void kernel_launch(void* const* d_in, const int* in_sizes, int n_in,
                              void* d_out, int out_size, void* d_ws, size_t ws_size,
                              hipStream_t stream){
  const float* x    = (const float*)d_in[0];
  const float* adap = (const float*)d_in[1];
  const float* wq   = (const float*)d_in[2];
  const float* wk   = (const float*)d_in[3];
  const float* wv   = (const float*)d_in[4];
  const float* wo   = (const float*)d_in[5];
  const float* lq1  = (const float*)d_in[6];
  const float* lq2  = (const float*)d_in[7];
  const float* lk1  = (const float*)d_in[8];
  const float* lk2  = (const float*)d_in[9];
  const float* lv1  = (const float*)d_in[10];
  const float* lv2  = (const float*)d_in[11];
  const float* lo1  = (const float*)d_in[12];
  const float* lo2  = (const float*)d_in[13];
  const float* gate = (const float*)d_in[14];
  const float* fcos = (const float*)d_in[15];
  const float* fsin = (const float*)d_in[16];

  const size_t MB = 1024 * 1024;
  char* ws = (char*)d_ws;
  u16*  Xcat = (u16*)(ws);                 // 4352x4096 bf16 (34 MB); later Q
  u16*  Wb   = (u16*)(ws + 34 * MB);       // 32 MB; later K
  u16*  xq   = (u16*)(ws + 66 * MB);       // 34 MB; later attn_out
  u16*  xk   = (u16*)(ws + 100 * MB);      // 34 MB
  u16*  xv   = (u16*)(ws + 134 * MB);      // 34 MB
  u16*  Vt   = (u16*)(ws + 168 * MB);      // 32 MB; tpart (16 MB f32) aliases (disjoint lifetimes)
  float* tpart = (float*)(ws + 168 * MB);  // [8][4096][128] f32
  u16*  l1b  = (u16*)(ws + 200 * MB);      // 1 MB
  u16*  AKb  = (u16*)(ws + 201 * MB);      // 0.5 MB
  u16*  AVb  = (u16*)(ws + 201 * MB + 512 * 1024); // 1 MB
  u16*  Qb = Xcat;
  u16*  Kb = Wb;
  u16*  attn = xq;
  float* out = (float*)d_out;

  dim3 blk(256);
  const u16* Xad = Xcat + (size_t)4096 * 4096;
  u16* xkad = xk + (size_t)4096 * 4096;
  u16* xvad = xv + (size_t)4096 * 4096;

  // 1: xcat + l1cat
  k_combo1<<<dim3(8960), blk, 0, stream>>>(x, adap, Xcat, lq1, lk1, lv1, l1b);
  // 2: f2b(wq) + split-K LoRA GEMM + adapter K/V GEMMs (read f32 weights)
  k_combo2<<<dim3(8576), blk, 0, stream>>>(wq, Wb, Xcat, l1b, tpart, Xad, wk, wv, xkad, xvad);
  // 3: Q projection
  gemm_nt256<<<dim3(256), dim3(512), 0, stream>>>(Xcat, Wb, xq, 4096, 4096, 1, 16);
  // 4: f2b(wk) + adapter reshape
  k_combo3<<<dim3(8320), blk, 0, stream>>>(wk, Wb, xkad, xvad, AKb, AVb);
  // 5: K projection
  gemm_nt256<<<dim3(256), dim3(512), 0, stream>>>(Xcat, Wb, xk, 4096, 4096, 1, 16);
  // 6: f2b(wv)
  k_f2bw<<<dim3(8192), blk, 0, stream>>>(wv, Wb);
  // 7: V projection (last reader of Xcat and of Wb=wv)
  gemm_nt256<<<dim3(256), dim3(512), 0, stream>>>(Xcat, Wb, xv, 4096, 4096, 1, 16);
  // 8: LoRA finishers: rope-q (xq->Qb=Xcat), rope-k (xk->Kb=Wb), add-v (in place)
  k_finish<<<dim3(24, 128), blk, 0, stream>>>(xq, xk, xv, tpart, lq2, lk2, lv2,
                                              fcos, fsin, Qb, Kb);
  // 9: V transpose (tpart consumed; Vt may overwrite it)
  k_vtrans<<<dim3(2048), blk, 0, stream>>>(xv, Vt);
  // 10: attention
  k_attn<<<dim3(1024), dim3(512), 0, stream>>>(Qb, Kb, Vt, AKb, AVb, gate, attn);
  // 11: f2b(wo) + lo1 pad
  k_combo7<<<dim3(8448), blk, 0, stream>>>(wo, Wb, lo1, l1b);
  // 12: output projection
  gemm_nt256<<<dim3(256), dim3(512), 0, stream>>>(attn, Wb, out, 4096, 4096, 0, 16);
  // 13: split-K LoRA GEMM on attn output
  k_gemm_lora<<<dim3(256), blk, 0, stream>>>(attn, l1b, tpart, 4096);
  // 14: final LoRA add into f32 output
  k_loraaddf<<<dim3(8, 128), blk, 0, stream>>>(out, tpart, lo2);
}

// Round 15
// 882.150 us; speedup vs baseline: 1.6745x; 1.0809x over previous
//
#include <hip/hip_runtime.h>
#include <stdint.h>

#define Bz 4
#define Sz 1024
#define DIMz 4096
#define Hz 32
#define HDz 128
#define ALz 10

typedef unsigned short u16;
typedef __attribute__((ext_vector_type(8))) short short8;
typedef __attribute__((ext_vector_type(4))) float fx4;

__device__ __forceinline__ u16 f2b(float f){
  union { float f; unsigned u; } v; v.f = f;
  unsigned r = v.u + 0x7FFFu + ((v.u >> 16) & 1u);
  return (u16)(r >> 16);
}
__device__ __forceinline__ float b2f(u16 h){
  union { unsigned u; float f; } v; v.u = ((unsigned)h) << 16; return v.f;
}
__device__ __forceinline__ short8 pack8(fx4 a, fx4 b){
  short8 v;
  v[0]=(short)f2b(a[0]); v[1]=(short)f2b(a[1]); v[2]=(short)f2b(a[2]); v[3]=(short)f2b(a[3]);
  v[4]=(short)f2b(b[0]); v[5]=(short)f2b(b[1]); v[6]=(short)f2b(b[2]); v[7]=(short)f2b(b[3]);
  return v;
}
__device__ __forceinline__ void gload16(const void* g, void* l){
  __builtin_amdgcn_global_load_lds(
    (const __attribute__((address_space(1))) uint32_t*)g,
    (__attribute__((address_space(3))) uint32_t*)l, 16, 0, 0);
}
__device__ __forceinline__ void bar(){
  asm volatile("" ::: "memory");
  __builtin_amdgcn_s_barrier();
  asm volatile("" ::: "memory");
}

// ---------- LDS swizzle helper (T2: byte ^= (row&7)<<4) ----------
__device__ __forceinline__ const short8* ldsRd(const u16* base, int rowBytes, int row, int colElem){
  unsigned byte = (unsigned)(row * rowBytes + colElem * 2);
  byte ^= (unsigned)((row & 7) << 4);
  return (const short8*)((const char*)base + byte);
}
__device__ __forceinline__ u16* psPtr(u16* base, int w, int row, int colElem){
  unsigned byte = (unsigned)(row * 128 + colElem * 2);
  byte ^= (unsigned)((row & 7) << 4);
  return (u16*)((char*)base + w * 2048 + byte);
}

// ================= aux bodies =================
__device__ __forceinline__ void f2b8_body(const float* __restrict__ src, u16* __restrict__ dst, int bid){
  size_t i = ((size_t)bid * 256 + threadIdx.x) * 8;
  *(short8*)(dst + i) = pack8(*(const fx4*)(src + i), *(const fx4*)(src + i + 4));
}

__device__ __forceinline__ void xcat_body(const float* __restrict__ x, const float* __restrict__ ad,
                                          u16* __restrict__ dst, int bid){
  size_t i = ((size_t)bid * 256 + threadIdx.x) * 8;
  int row = (int)(i >> 12), col = (int)(i & 4095);
  short8 v = {0,0,0,0,0,0,0,0};
  const float* s = nullptr;
  if (row < 4096) s = x + i;
  else if (row < 4096 + Bz*ALz) s = ad + (size_t)(row - 4096) * 4096 + col;
  if (s) v = pack8(*(const fx4*)s, *(const fx4*)(s + 4));
  *(short8*)(dst + i) = v;
}

__device__ __forceinline__ void l1cat_body(const float* __restrict__ a, const float* __restrict__ b,
                                           const float* __restrict__ c, u16* __restrict__ dst, int bid){
  size_t i = ((size_t)bid * 256 + threadIdx.x) * 8;
  int row = (int)(i >> 12), col = (int)(i & 4095);
  short8 v = {0,0,0,0,0,0,0,0};
  const float* s = nullptr;
  if (row < 16) s = a + i;
  else if (row < 32) s = b + (size_t)(row - 16) * 4096 + col;
  else if (row < 48) s = c + (size_t)(row - 32) * 4096 + col;
  if (s) v = pack8(*(const fx4*)s, *(const fx4*)(s + 4));
  *(short8*)(dst + i) = v;
}

__device__ __forceinline__ void lo1pad_body(const float* __restrict__ src, u16* __restrict__ dst, int bid){
  size_t i = ((size_t)bid * 256 + threadIdx.x) * 8;
  int row = (int)(i >> 12);
  short8 v = {0,0,0,0,0,0,0,0};
  if (row < 16) v = pack8(*(const fx4*)(src + i), *(const fx4*)(src + i + 4));
  *(short8*)(dst + i) = v;
}

// split-K LoRA-l1 GEMM body (128^2 tile, K-slice 512) — writes f32 partials
__device__ __forceinline__ void gemm_lora_body(u16* shA, u16* shB,
    const u16* __restrict__ A, const u16* __restrict__ Bm, float* __restrict__ Cpart,
    int K, int bid2){
  const int tid = threadIdx.x;
  const int w = tid >> 6, l = tid & 63;
  const int lrow = l & 15, lgrp = l >> 4;
  const int ks = bid2 & 7;
  const int bm = (bid2 >> 3) * 128;
  const int wr = (w >> 1) * 64, wc = (w & 1) * 64;

  const fx4 fz = {0.f, 0.f, 0.f, 0.f};
  fx4 acc[4][4];
#pragma unroll
  for (int i = 0; i < 4; i++)
#pragma unroll
    for (int j = 0; j < 4; j++) acc[i][j] = fz;

  const u16* Abase = A + (size_t)bm * K;
  const int kbeg = ks * 512, kend = kbeg + 512;

  for (int k0 = kbeg; k0 < kend; k0 += 64){
    __syncthreads();
#pragma unroll
    for (int i = 0; i < 4; i++){
      int c = i * 256 + tid;
      int row = c >> 3, cs = c & 7;
      int off = (cs ^ (row & 7)) << 3;
      gload16(Abase + (size_t)row * K + k0 + off, shA + c * 8);
      gload16(Bm + (size_t)row * K + k0 + off, shB + c * 8);
    }
    __syncthreads();
#pragma unroll
    for (int kk = 0; kk < 2; kk++){
      short8 a[4], b[4];
#pragma unroll
      for (int i = 0; i < 4; i++) a[i] = *ldsRd(shA, 128, wr + i*16 + lrow, kk*32 + lgrp*8);
#pragma unroll
      for (int j = 0; j < 4; j++) b[j] = *ldsRd(shB, 128, wc + j*16 + lrow, kk*32 + lgrp*8);
#pragma unroll
      for (int i = 0; i < 4; i++)
#pragma unroll
        for (int j = 0; j < 4; j++)
          acc[i][j] = __builtin_amdgcn_mfma_f32_16x16x32_bf16(a[i], b[j], acc[i][j], 0, 0, 0);
    }
  }

  float* C = Cpart + (size_t)ks * 4096 * 128;
#pragma unroll
  for (int i = 0; i < 4; i++)
#pragma unroll
    for (int r = 0; r < 4; r++){
      int gm = bm + wr + i*16 + lgrp*4 + r;
      float* crow = C + (size_t)gm * 128 + wc + lrow;
#pragma unroll
      for (int j = 0; j < 4; j++) crow[j*16] = acc[i][j][r];
    }
}

// split-K thin adapter GEMM body (f32 weights, K-slice 512) — writes f32 partials [8][48][4096]
__device__ __forceinline__ void adgemm_ks_body(const u16* __restrict__ A, const float* __restrict__ Bw,
    float* __restrict__ Cpart, int K, int bid512){
  const int tid = threadIdx.x;
  const int w = tid >> 6, l = tid & 63;
  const int lrow = l & 15, lgrp = l >> 4;
  const int ks = bid512 >> 6;
  const int n0 = (bid512 & 63) * 64 + w * 16;

  const fx4 fz = {0.f, 0.f, 0.f, 0.f};
  fx4 acc[3];
#pragma unroll
  for (int i = 0; i < 3; i++) acc[i] = fz;

  const float* Brow = Bw + (size_t)(n0 + lrow) * K + ks * 512 + lgrp * 8;
  const u16* Arow = A + (size_t)lrow * K + ks * 512 + lgrp * 8;
#pragma unroll 2
  for (int k0 = 0; k0 < 512; k0 += 32){
    fx4 b0 = *(const fx4*)(Brow + k0);
    fx4 b1 = *(const fx4*)(Brow + k0 + 4);
    short8 b = pack8(b0, b1);
#pragma unroll
    for (int mf = 0; mf < 3; mf++){
      short8 a = *(const short8*)(Arow + (size_t)mf * 16 * K + k0);
      acc[mf] = __builtin_amdgcn_mfma_f32_16x16x32_bf16(a, b, acc[mf], 0, 0, 0);
    }
  }
  float* C = Cpart + (size_t)ks * 48 * 4096;
#pragma unroll
  for (int mf = 0; mf < 3; mf++)
#pragma unroll
    for (int r = 0; r < 4; r++)
      C[(size_t)(mf * 16 + lgrp * 4 + r) * 4096 + n0 + lrow] = acc[mf][r];
}

// adapter reshape from f32 partials: AK (B,H,16,HD), AVt (B,H,HD,32)
__device__ __forceinline__ void adresh_body(const float* __restrict__ apK, const float* __restrict__ apV,
    u16* __restrict__ AK, u16* __restrict__ AVt, int bh){
  const int h = bh & 31;
  const int tid = threadIdx.x;
#pragma unroll
  for (int i = 0; i < 8; i++){
    int e = i * 256 + tid;
    int jj = e >> 7, d = e & 127;
    float a = 0.f;
    if (jj < ALz){
      int brow = (bh >> 5) * ALz + jj;
#pragma unroll
      for (int p = 0; p < 8; p++)
        a += apK[((size_t)p * 48 + brow % 48) * 4096 + h * HDz + d];
    }
    AK[((size_t)bh * 16 + jj) * HDz + d] = (jj < ALz) ? f2b(a) : (u16)0;
  }
#pragma unroll
  for (int i = 0; i < 16; i++){
    int e = i * 256 + tid;
    int d = e >> 5, jj = e & 31;
    float a = 0.f;
    if (jj < ALz){
      int brow = (bh >> 5) * ALz + jj;
#pragma unroll
      for (int p = 0; p < 8; p++)
        a += apV[((size_t)p * 48 + brow % 48) * 4096 + h * HDz + d];
    }
    AVt[((size_t)bh * HDz + d) * 32 + jj] = (jj < ALz) ? f2b(a) : (u16)0;
  }
}

// ================= combo kernels =================
__global__ __launch_bounds__(256)
void k_combo1(const float* x, const float* ad, u16* Xcat,
              const float* lq1, const float* lk1, const float* lv1, u16* l1b){
  int bid = blockIdx.x;
  if (bid < 8704) xcat_body(x, ad, Xcat, bid);
  else l1cat_body(lq1, lk1, lv1, l1b, bid - 8704);
}

// f2b(wq) + split-K LoRA GEMM + split-K adapter K/V GEMMs (f32 weights)
__global__ __launch_bounds__(256)
void k_combo2(const float* wq, u16* Wb,
              const u16* Xcat, const u16* l1b, float* tpart,
              const u16* Xad, const float* wk, const float* wv,
              float* apK, float* apV){
  __shared__ __align__(16) u16 sh[2][128][64];
  int bid = blockIdx.x;
  if (bid < 8192) f2b8_body(wq, Wb, bid);
  else if (bid < 8448) gemm_lora_body(&sh[0][0][0], &sh[1][0][0], Xcat, l1b, tpart, 4096, bid - 8192);
  else if (bid < 8960) adgemm_ks_body(Xad, wk, apK, 4096, bid - 8448);
  else adgemm_ks_body(Xad, wv, apV, 4096, bid - 8960);
}

// f2b(wk) + adapter reshape (partials ready since combo2)
__global__ __launch_bounds__(256)
void k_combo3(const float* wk, u16* Wb,
              const float* apK, const float* apV, u16* AK, u16* AVt){
  int bid = blockIdx.x;
  if (bid < 8192) f2b8_body(wk, Wb, bid);
  else adresh_body(apK, apV, AK, AVt, bid - 8192);
}

// f2b(wv) alone
__global__ __launch_bounds__(256)
void k_f2bw(const float* w, u16* Wb){ f2b8_body(w, Wb, blockIdx.x); }

// LoRA finishers AFTER V projection. Grid (24, 128): x = kind*8+slab, y = 32-row m-block.
__global__ __launch_bounds__(256)
void k_finish(const u16* __restrict__ xq, const u16* __restrict__ xk, u16* __restrict__ xv,
              const float* __restrict__ tpart,
              const float* __restrict__ lq2, const float* __restrict__ lk2,
              const float* __restrict__ lv2,
              const float* __restrict__ fcos, const float* __restrict__ fsin,
              u16* __restrict__ Qb, u16* __restrict__ Kb){
  __shared__ float ts[32][16];
  const int kind = blockIdx.x >> 3;   // 0=q,1=k,2=v
  const int slab = blockIdx.x & 7;
  const int m0 = blockIdx.y * 32;
  const int tid = threadIdx.x;
  const float* l2 = (kind == 0) ? lq2 : (kind == 1) ? lk2 : lv2;

#pragma unroll
  for (int rep = 0; rep < 2; rep++){
    int id2 = rep * 256 + tid;
    int mi = id2 >> 4, c = id2 & 15;
    float a = 0.f;
#pragma unroll
    for (int p = 0; p < 8; p++)
      a += tpart[((size_t)p * 4096 + m0 + mi) * 128 + kind * 16 + c];
    ts[mi][c] = a;
  }
  __syncthreads();

  const int o0 = slab * 512 + tid * 2;
  fx4 l2r0[4], l2r1[4];
#pragma unroll
  for (int q = 0; q < 4; q++){
    l2r0[q] = *(const fx4*)(l2 + (size_t)o0 * 16 + q * 4);
    l2r1[q] = *(const fx4*)(l2 + (size_t)(o0 + 1) * 16 + q * 4);
  }

  const int h = o0 >> 7, dd = o0 & 127, j = dd >> 1;

  for (int mi = 0; mi < 32; mi++){
    const int m = m0 + mi;
    float ss0 = 0.f, ss1 = 0.f;
#pragma unroll
    for (int q = 0; q < 4; q++){
      fx4 tq = *(const fx4*)&ts[mi][q * 4];
      ss0 += tq[0]*l2r0[q][0] + tq[1]*l2r0[q][1] + tq[2]*l2r0[q][2] + tq[3]*l2r0[q][3];
      ss1 += tq[0]*l2r1[q][0] + tq[1]*l2r1[q][1] + tq[2]*l2r1[q][2] + tq[3]*l2r1[q][3];
    }
    if (kind < 2){
      const u16* xin = (kind == 0) ? xq : xk;
      u16* outp = (kind == 0) ? Qb : Kb;
      unsigned cur = *(const unsigned*)&xin[(size_t)m * 4096 + o0];
      float v0 = b2f((u16)(cur & 0xFFFF)) + ss0;
      float v1 = b2f((u16)(cur >> 16)) + ss1;
      const int b = m >> 10, s = m & 1023;
      float c = fcos[s * 64 + j], sn = fsin[s * 64 + j];
      float re = v0 * c - v1 * sn;
      float im = v0 * sn + v1 * c;
      size_t oi = (((size_t)(b * Hz + h)) * Sz + s) * HDz + dd;
      *(unsigned*)&outp[oi] = (unsigned)f2b(re) | ((unsigned)f2b(im) << 16);
    } else {
      u16* yp = xv + (size_t)m * 4096 + o0;
      unsigned cur = *(unsigned*)yp;
      float v0 = b2f((u16)(cur & 0xFFFF)) + ss0;
      float v1 = b2f((u16)(cur >> 16)) + ss1;
      *(unsigned*)yp = (unsigned)f2b(v0) | ((unsigned)f2b(v1) << 16);
    }
  }
}

__global__ __launch_bounds__(256)
void k_combo7(const float* wo, u16* Wb, const float* lo1, u16* l1b){
  int bid = blockIdx.x;
  if (bid < 8192) f2b8_body(wo, Wb, bid);
  else lo1pad_body(lo1, l1b, bid - 8192);
}

__global__ __launch_bounds__(256)
void k_gemm_lora(const u16* A, const u16* Bm, float* Cpart, int K){
  __shared__ __align__(16) u16 sh[2][128][64];
  gemm_lora_body(&sh[0][0][0], &sh[1][0][0], A, Bm, Cpart, K, blockIdx.x);
}

// final LoRA add into f32 output. Grid (8, 128).
__global__ __launch_bounds__(256)
void k_loraaddf(float* __restrict__ y, const float* __restrict__ tp, const float* __restrict__ l2){
  __shared__ float ts[32][16];
  const int slab = blockIdx.x;
  const int m0 = blockIdx.y * 32;
  const int tid = threadIdx.x;
#pragma unroll
  for (int rep = 0; rep < 2; rep++){
    int id2 = rep * 256 + tid;
    int mi = id2 >> 4, c = id2 & 15;
    float a = 0.f;
#pragma unroll
    for (int p = 0; p < 8; p++)
      a += tp[((size_t)p * 4096 + m0 + mi) * 128 + c];
    ts[mi][c] = a;
  }
  __syncthreads();

  const int o0 = slab * 512 + tid * 2;
  fx4 l2r0[4], l2r1[4];
#pragma unroll
  for (int q = 0; q < 4; q++){
    l2r0[q] = *(const fx4*)(l2 + (size_t)o0 * 16 + q * 4);
    l2r1[q] = *(const fx4*)(l2 + (size_t)(o0 + 1) * 16 + q * 4);
  }

  for (int mi = 0; mi < 32; mi++){
    float ss0 = 0.f, ss1 = 0.f;
#pragma unroll
    for (int q = 0; q < 4; q++){
      fx4 tq = *(const fx4*)&ts[mi][q * 4];
      ss0 += tq[0]*l2r0[q][0] + tq[1]*l2r0[q][1] + tq[2]*l2r0[q][2] + tq[3]*l2r0[q][3];
      ss1 += tq[0]*l2r1[q][0] + tq[1]*l2r1[q][1] + tq[2]*l2r1[q][2] + tq[3]*l2r1[q][3];
    }
    float* yp = y + (size_t)(m0 + mi) * 4096 + o0;
    yp[0] += ss0;
    yp[1] += ss1;
  }
}

// ---------- V: (B,S,H,HD) -> Vt (B,H,HD,S) ----------
__global__ __launch_bounds__(256)
void k_vtrans(const u16* __restrict__ x, u16* __restrict__ vt){
  __shared__ __align__(16) u16 tile[64][128];
  int bid = blockIdx.x;
  int bh = bid >> 4;
  int b = bh >> 5, h = bh & 31;
  int s0 = (bid & 15) * 64;
  int tid = threadIdx.x;
#pragma unroll
  for (int i = 0; i < 4; i++){
    int c = i * 256 + tid;
    int ss = c >> 4, d8 = (c & 15) << 3;
    *(short8*)&tile[ss][d8] =
      *(const short8*)&x[(size_t)(b * Sz + s0 + ss) * DIMz + h * HDz + d8];
  }
  __syncthreads();
#pragma unroll
  for (int i = 0; i < 4; i++){
    int c = i * 256 + tid;
    int d = c >> 3, s8 = (c & 7) << 3;
    short8 v;
#pragma unroll
    for (int k = 0; k < 8; k++) v[k] = (short)tile[s8 + k][d];
    *(short8*)&vt[((size_t)bh * HDz + d) * Sz + s0 + s8] = v;
  }
}

// ---------- 256x256 8-phase counted-vmcnt NT bf16 GEMM ----------
#define PHASE(BUF, P, STAGE_STMT, VM_STMT)                                          \
  {                                                                                 \
    if ((P) == 0){                                                                  \
      _Pragma("unroll")                                                             \
      for (int nj = 0; nj < 4; nj++)                                                \
        _Pragma("unroll")                                                           \
        for (int kk = 0; kk < 2; kk++)                                              \
          bf[nj][kk] = *ldsRd(&lds[BUF][2 + (wn >> 1)][0][0], 128,                  \
                              (wn & 1) * 64 + nj * 16 + lrow, kk * 32 + lgrp * 8);  \
    }                                                                               \
    short8 af[2][2];                                                                \
    _Pragma("unroll")                                                               \
    for (int m2 = 0; m2 < 2; m2++)                                                  \
      _Pragma("unroll")                                                             \
      for (int kk = 0; kk < 2; kk++)                                                \
        af[m2][kk] = *ldsRd(&lds[BUF][wm][0][0], 128,                               \
                            ((P) * 2 + m2) * 16 + lrow, kk * 32 + lgrp * 8);        \
    STAGE_STMT;                                                                     \
    bar();                                                                          \
    __builtin_amdgcn_s_setprio(1);                                                  \
    _Pragma("unroll")                                                               \
    for (int m2 = 0; m2 < 2; m2++)                                                  \
      _Pragma("unroll")                                                             \
      for (int nj = 0; nj < 4; nj++)                                                \
        _Pragma("unroll")                                                           \
        for (int kk = 0; kk < 2; kk++)                                              \
          acc[(P) * 2 + m2][nj] = __builtin_amdgcn_mfma_f32_16x16x32_bf16(          \
              af[m2][kk], bf[nj][kk], acc[(P) * 2 + m2][nj], 0, 0, 0);              \
    __builtin_amdgcn_s_setprio(0);                                                  \
    VM_STMT;                                                                        \
    bar();                                                                          \
  }

__global__ __launch_bounds__(512, 2)
void gemm_nt256(const u16* __restrict__ A, const u16* __restrict__ Bm,
                void* __restrict__ Cp, int N, int K, int outBf16, int nbx){
  __shared__ __align__(16) u16 lds[2][4][128][64];
  const int tid = threadIdx.x;
  const int l = tid & 63, w = tid >> 6;
  const int lrow = l & 15, lgrp = l >> 4;
  const int wm = w >> 2, wn = w & 3;

  const int nwg = gridDim.x;
  const int cpx = nwg >> 3;
  const int swz = (blockIdx.x & 7) * cpx + (blockIdx.x >> 3);
  const int by = swz / nbx, bx = swz - by * nbx;
  const int bm = by << 8, bn = bx << 8;

  const u16* A0s = A  + (size_t)bm * K;
  const u16* A1s = A0s + (size_t)128 * K;
  const u16* B0s = Bm + (size_t)bn * K;
  const u16* B1s = B0s + (size_t)128 * K;
  const int nt = K >> 6;

  const fx4 fz = {0.f, 0.f, 0.f, 0.f};
  fx4 acc[8][4];
#pragma unroll
  for (int i = 0; i < 8; i++)
#pragma unroll
    for (int j = 0; j < 4; j++) acc[i][j] = fz;

  auto STAGEH = [&](int buf, int reg, const u16* src, int t){
#pragma unroll
    for (int r = 0; r < 2; r++){
      int c = r * 512 + tid;
      int row = c >> 3, cs = c & 7;
      int off = (cs ^ (row & 7)) << 3;
      gload16(src + (size_t)row * K + t * 64 + off, &lds[buf][reg][0][0] + c * 8);
    }
  };

  STAGEH(0, 0, A0s, 0); STAGEH(0, 1, A1s, 0);
  STAGEH(0, 2, B0s, 0); STAGEH(0, 3, B1s, 0);
  STAGEH(1, 2, B0s, 1); STAGEH(1, 3, B1s, 1);
  asm volatile("s_waitcnt vmcnt(4)" ::: "memory");
  bar();

  short8 bf[4][2];
  const int ni = nt >> 1;
  for (int i = 0; i < ni; i++){
    const int t0 = 2 * i, t1 = 2 * i + 1;
    const bool more = (i < ni - 1);
    PHASE(0, 0, { STAGEH(1, 0, A0s, t1); }, {});
    PHASE(0, 1, { STAGEH(1, 1, A1s, t1); }, {});
    PHASE(0, 2, { if (more) STAGEH(0, 2, B0s, t0 + 2); }, {});
    PHASE(0, 3, { if (more) STAGEH(0, 3, B1s, t0 + 2); },
          { if (more) { asm volatile("s_waitcnt vmcnt(4)" ::: "memory"); }
            else      { asm volatile("s_waitcnt vmcnt(0)" ::: "memory"); } });
    PHASE(1, 0, { if (more) STAGEH(0, 0, A0s, t0 + 2); }, {});
    PHASE(1, 1, { if (more) STAGEH(0, 1, A1s, t0 + 2); }, {});
    PHASE(1, 2, { if (more) STAGEH(1, 2, B0s, t1 + 2); }, {});
    PHASE(1, 3, { if (more) STAGEH(1, 3, B1s, t1 + 2); },
          { if (more) { asm volatile("s_waitcnt vmcnt(4)" ::: "memory"); } });
  }

  if (outBf16){
    u16* C = (u16*)Cp;
#pragma unroll
    for (int mi = 0; mi < 8; mi++)
#pragma unroll
      for (int r = 0; r < 4; r++){
        int gm = bm + wm * 128 + mi * 16 + lgrp * 4 + r;
        u16* crow = C + (size_t)gm * N + bn + wn * 64 + lrow;
#pragma unroll
        for (int nj = 0; nj < 4; nj++) crow[nj * 16] = f2b(acc[mi][nj][r]);
      }
  } else {
    float* C = (float*)Cp;
#pragma unroll
    for (int mi = 0; mi < 8; mi++)
#pragma unroll
      for (int r = 0; r < 4; r++){
        int gm = bm + wm * 128 + mi * 16 + lgrp * 4 + r;
        float* crow = C + (size_t)gm * N + bn + wn * 64 + lrow;
#pragma unroll
        for (int nj = 0; nj < 4; nj++) crow[nj * 16] = acc[mi][nj][r];
      }
  }
}

// ---------- flash attention + gated adapter attention ----------
__global__ __launch_bounds__(512)
void k_attn(const u16* __restrict__ Q, const u16* __restrict__ Kg,
            const u16* __restrict__ Vt, const u16* __restrict__ AKg,
            const u16* __restrict__ AVg, const float* __restrict__ gate,
            u16* __restrict__ outp){
  __shared__ __align__(16) u16 Ks[2][64][128];
  __shared__ __align__(16) u16 Vs[2][128][64];
  __shared__ __align__(16) u16 Ps[8][16][64];

  const int blk = blockIdx.x;
  const int jj = blk >> 3;
  const int bh = (blk & 7) * 16 + (jj & 15);
  const int bx = jj >> 4;
  const int b = bh >> 5, h = bh & 31;
  const int q0 = bx * 128;
  const int tid = threadIdx.x;
  const int w = tid >> 6, l = tid & 63;
  const int lrow = l & 15, lgrp = l >> 4;

  const u16* Qb = Q  + (size_t)bh * (Sz * HDz) + (size_t)q0 * HDz;
  const u16* Kb = Kg + (size_t)bh * (Sz * HDz);
  const u16* Vb = Vt + (size_t)bh * (HDz * Sz);
  u16* PsB = &Ps[0][0][0];

  short8 aq[4];
#pragma unroll
  for (int kk = 0; kk < 4; kk++)
    aq[kk] = *(const short8*)&Qb[(size_t)(w*16 + lrow) * HDz + kk*32 + lgrp*8];

  const fx4 fz = {0.f, 0.f, 0.f, 0.f};
  fx4 o[8];
#pragma unroll
  for (int i = 0; i < 8; i++) o[i] = fz;
  float mrow[4], lsum[4];
#pragma unroll
  for (int r = 0; r < 4; r++){ mrow[r] = -1e30f; lsum[r] = 0.f; }

  const float scale2 = 0.088388347648318447f * 1.4426950408889634f;
  const int qwbase = q0 + w * 16;
  const int qrowbase = qwbase + lgrp * 4;
  const int ktiles = 2 * bx + 2;

  auto STAGE = [&](int buf, int kt){
    const int k0 = kt * 64;
#pragma unroll
    for (int r = 0; r < 2; r++){
      int c = r * 512 + tid;
      int row = c >> 4, cs = c & 15;
      int gcs = cs ^ (row & 7);
      gload16(Kb + (size_t)(k0 + row) * HDz + gcs * 8, ((u16*)&Ks[buf][0][0]) + c * 8);
    }
#pragma unroll
    for (int r = 0; r < 2; r++){
      int c = r * 512 + tid;
      int row = c >> 3, cs = c & 7;
      int gcs = cs ^ (row & 7);
      gload16(Vb + (size_t)row * Sz + k0 + gcs * 8, ((u16*)&Vs[buf][0][0]) + c * 8);
    }
  };

  STAGE(0, 0);
  asm volatile("s_waitcnt vmcnt(0)" ::: "memory");
  bar();

  for (int kt = 0; kt < ktiles; kt++){
    const int cur = kt & 1;
    if (kt + 1 < ktiles) STAGE(cur ^ 1, kt + 1);
    const int k0 = kt * 64;

    if (k0 <= qwbase + 15){
      fx4 sc[4];
#pragma unroll
      for (int j = 0; j < 4; j++) sc[j] = fz;
      __builtin_amdgcn_s_setprio(1);
#pragma unroll
      for (int kk = 0; kk < 4; kk++){
#pragma unroll
        for (int j = 0; j < 4; j++){
          short8 bk = *ldsRd(&Ks[cur][0][0], 256, j*16 + lrow, kk*32 + lgrp*8);
          sc[j] = __builtin_amdgcn_mfma_f32_16x16x32_bf16(aq[kk], bk, sc[j], 0, 0, 0);
        }
      }
      __builtin_amdgcn_s_setprio(0);
      const bool domask = (k0 + 63 > qwbase);
      float tm[4];
#pragma unroll
      for (int r = 0; r < 4; r++){
        float mx = -1e30f;
#pragma unroll
        for (int j = 0; j < 4; j++){
          float v = sc[j][r] * scale2;
          if (domask){
            int kcol = k0 + j*16 + lrow;
            if (kcol > qrowbase + r) v = -1e30f;
          }
          sc[j][r] = v;
          mx = fmaxf(mx, v);
        }
#pragma unroll
        for (int d = 1; d < 16; d <<= 1) mx = fmaxf(mx, __shfl_xor(mx, d));
        tm[r] = mx;
      }
      if (!__all(tm[0] <= mrow[0] + 11.5f && tm[1] <= mrow[1] + 11.5f &&
                 tm[2] <= mrow[2] + 11.5f && tm[3] <= mrow[3] + 11.5f)){
        float esc[4];
#pragma unroll
        for (int r = 0; r < 4; r++){
          float nm = fmaxf(mrow[r], tm[r]);
          esc[r] = exp2f(mrow[r] - nm);
          mrow[r] = nm;
          lsum[r] *= esc[r];
        }
#pragma unroll
        for (int j = 0; j < 8; j++)
#pragma unroll
          for (int r = 0; r < 4; r++) o[j][r] *= esc[r];
      }
#pragma unroll
      for (int r = 0; r < 4; r++){
        float s = 0.f;
#pragma unroll
        for (int j = 0; j < 4; j++){
          float p = exp2f(sc[j][r] - mrow[r]);
          sc[j][r] = p;
          s += p;
        }
#pragma unroll
        for (int d = 1; d < 16; d <<= 1) s += __shfl_xor(s, d);
        lsum[r] += s;
      }
#pragma unroll
      for (int j = 0; j < 4; j++)
#pragma unroll
        for (int r = 0; r < 4; r++)
          *psPtr(PsB, w, lgrp*4 + r, j*16 + lrow) = f2b(sc[j][r]);
      __builtin_amdgcn_s_setprio(1);
#pragma unroll
      for (int kk = 0; kk < 2; kk++){
        short8 ap = *(const short8*)psPtr(PsB, w, lrow, kk*32 + lgrp*8);
#pragma unroll
        for (int j = 0; j < 8; j++){
          short8 bv = *ldsRd(&Vs[cur][0][0], 128, j*16 + lrow, kk*32 + lgrp*8);
          o[j] = __builtin_amdgcn_mfma_f32_16x16x32_bf16(ap, bv, o[j], 0, 0, 0);
        }
      }
      __builtin_amdgcn_s_setprio(0);
    }

    asm volatile("s_waitcnt vmcnt(0)" ::: "memory");
    bar();
  }

#pragma unroll
  for (int j = 0; j < 8; j++)
#pragma unroll
    for (int r = 0; r < 4; r++) o[j][r] /= lsum[r];

  fx4 s2 = fz;
  const u16* AKb = AKg + (size_t)bh * (16 * HDz);
#pragma unroll
  for (int kk = 0; kk < 4; kk++){
    short8 bk = *(const short8*)&AKb[(size_t)lrow * HDz + kk*32 + lgrp*8];
    s2 = __builtin_amdgcn_mfma_f32_16x16x32_bf16(aq[kk], bk, s2, 0, 0, 0);
  }
  const float g = tanhf(gate[h]);
#pragma unroll
  for (int r = 0; r < 4; r++){
    float v = s2[r] * scale2;
    if (lrow >= ALz) v = -1e30f;
    float mx = v;
#pragma unroll
    for (int d = 1; d < 16; d <<= 1) mx = fmaxf(mx, __shfl_xor(mx, d));
    float p = exp2f(v - mx);
    float s = p;
#pragma unroll
    for (int d = 1; d < 16; d <<= 1) s += __shfl_xor(s, d);
    float p2 = g * p / s;
    *psPtr(PsB, w, lgrp*4 + r, lrow) = f2b(p2);
    *psPtr(PsB, w, lgrp*4 + r, 16 + lrow) = 0;
  }
  {
    const u16* AVb = AVg + (size_t)bh * (HDz * 32);
    short8 ap = *(const short8*)psPtr(PsB, w, lrow, lgrp*8);
#pragma unroll
    for (int j = 0; j < 8; j++){
      short8 bv = *(const short8*)&AVb[(size_t)(j*16 + lrow) * 32 + lgrp*8];
      o[j] = __builtin_amdgcn_mfma_f32_16x16x32_bf16(ap, bv, o[j], 0, 0, 0);
    }
  }

  u16* ob = outp + (size_t)(b * Sz + q0 + w * 16) * DIMz + h * HDz;
  const int rr = l >> 2, cc = (l & 3) * 16;
#pragma unroll
  for (int half = 0; half < 2; half++){
#pragma unroll
    for (int j = 0; j < 4; j++)
#pragma unroll
      for (int r = 0; r < 4; r++)
        Ps[w][lgrp*4 + r][j*16 + lrow] = f2b(o[half*4 + j][r]);
    short8 s0 = *(const short8*)&Ps[w][rr][cc];
    short8 s1 = *(const short8*)&Ps[w][rr][cc + 8];
    *(short8*)&ob[(size_t)rr * DIMz + half*64 + cc] = s0;
    *(short8*)&ob[(size_t)rr * DIMz + half*64 + cc + 8] = s1;
  }
}

// ---------- host ----------
extern "C" void kernel_launch(void* const* d_in, const int* in_sizes, int n_in,
                              void* d_out, int out_size, void* d_ws, size_t ws_size,
                              hipStream_t stream){
  const float* x    = (const float*)d_in[0];
  const float* adap = (const float*)d_in[1];
  const float* wq   = (const float*)d_in[2];
  const float* wk   = (const float*)d_in[3];
  const float* wv   = (const float*)d_in[4];
  const float* wo   = (const float*)d_in[5];
  const float* lq1  = (const float*)d_in[6];
  const float* lq2  = (const float*)d_in[7];
  const float* lk1  = (const float*)d_in[8];
  const float* lk2  = (const float*)d_in[9];
  const float* lv1  = (const float*)d_in[10];
  const float* lv2  = (const float*)d_in[11];
  const float* lo1  = (const float*)d_in[12];
  const float* lo2  = (const float*)d_in[13];
  const float* gate = (const float*)d_in[14];
  const float* fcos = (const float*)d_in[15];
  const float* fsin = (const float*)d_in[16];

  const size_t MB = 1024 * 1024;
  char* ws = (char*)d_ws;
  u16*  Xcat = (u16*)(ws);                 // 4352x4096 bf16 (34 MB); later Q
  u16*  Wb   = (u16*)(ws + 34 * MB);       // 32 MB; later K
  u16*  xq   = (u16*)(ws + 66 * MB);       // 34 MB; later attn_out
  u16*  xk   = (u16*)(ws + 100 * MB);      // 34 MB
  u16*  xv   = (u16*)(ws + 134 * MB);      // 34 MB
  u16*  Vt   = (u16*)(ws + 168 * MB);      // 32 MB total region
  float* tpart = (float*)(ws + 168 * MB);  // [8][4096][128] f32 (16 MB; dead before vtrans)
  float* apK  = (float*)(ws + 184 * MB);   // [8][48][4096] f32 (6.3 MB; dead after combo3)
  float* apV  = (float*)(ws + 190 * MB + 512 * 1024); // 6.3 MB
  u16*  l1b  = (u16*)(ws + 200 * MB);      // 1 MB
  u16*  AKb  = (u16*)(ws + 201 * MB);      // 0.5 MB
  u16*  AVb  = (u16*)(ws + 201 * MB + 512 * 1024); // 1 MB
  u16*  Qb = Xcat;
  u16*  Kb = Wb;
  u16*  attn = xq;
  float* out = (float*)d_out;

  dim3 blk(256);
  const u16* Xad = Xcat + (size_t)4096 * 4096;

  // 1: xcat + l1cat
  k_combo1<<<dim3(8960), blk, 0, stream>>>(x, adap, Xcat, lq1, lk1, lv1, l1b);
  // 2: f2b(wq) + split-K LoRA GEMM + split-K adapter K/V GEMMs
  k_combo2<<<dim3(9472), blk, 0, stream>>>(wq, Wb, Xcat, l1b, tpart, Xad, wk, wv, apK, apV);
  // 3: Q projection
  gemm_nt256<<<dim3(256), dim3(512), 0, stream>>>(Xcat, Wb, xq, 4096, 4096, 1, 16);
  // 4: f2b(wk) + adapter reshape (sums partials)
  k_combo3<<<dim3(8320), blk, 0, stream>>>(wk, Wb, apK, apV, AKb, AVb);
  // 5: K projection
  gemm_nt256<<<dim3(256), dim3(512), 0, stream>>>(Xcat, Wb, xk, 4096, 4096, 1, 16);
  // 6: f2b(wv)
  k_f2bw<<<dim3(8192), blk, 0, stream>>>(wv, Wb);
  // 7: V projection (last reader of Xcat and of Wb=wv)
  gemm_nt256<<<dim3(256), dim3(512), 0, stream>>>(Xcat, Wb, xv, 4096, 4096, 1, 16);
  // 8: LoRA finishers: rope-q (xq->Qb=Xcat), rope-k (xk->Kb=Wb), add-v (in place)
  k_finish<<<dim3(24, 128), blk, 0, stream>>>(xq, xk, xv, tpart, lq2, lk2, lv2,
                                              fcos, fsin, Qb, Kb);
  // 9: V transpose (tpart/apK/apV consumed; Vt overwrites them)
  k_vtrans<<<dim3(2048), blk, 0, stream>>>(xv, Vt);
  // 10: attention
  k_attn<<<dim3(1024), dim3(512), 0, stream>>>(Qb, Kb, Vt, AKb, AVb, gate, attn);
  // 11: f2b(wo) + lo1 pad
  k_combo7<<<dim3(8448), blk, 0, stream>>>(wo, Wb, lo1, l1b);
  // 12: output projection
  gemm_nt256<<<dim3(256), dim3(512), 0, stream>>>(attn, Wb, out, 4096, 4096, 0, 16);
  // 13: split-K LoRA GEMM on attn output (tpart region free again after vtrans? no:
  //     Vt still live for attn — but attn done by now; tpart overwrites Vt space safely)
  k_gemm_lora<<<dim3(256), blk, 0, stream>>>(attn, l1b, tpart, 4096);
  // 14: final LoRA add into f32 output
  k_loraaddf<<<dim3(8, 128), blk, 0, stream>>>(out, tpart, lo2);
}